// Round 17
// baseline (362.837 us; speedup 1.0000x reference)
//
#include <hip/hip_runtime.h>
#include <hip/hip_bf16.h>

constexpr int NN = 8192;
using uint = unsigned int;

typedef __bf16 bf16x8 __attribute__((ext_vector_type(8)));
typedef float f32x4 __attribute__((ext_vector_type(4)));
typedef float f32x16 __attribute__((ext_vector_type(16)));
typedef unsigned short ushort8_t __attribute__((ext_vector_type(8)));

__device__ __forceinline__ float eluf(float z) { return z > 0.f ? z : __expf(z) - 1.f; }

__device__ __forceinline__ unsigned short bf16_hi(float v) {
  unsigned u = __float_as_uint(v);
  unsigned r = u + 0x7fffu + ((u >> 16) & 1u);
  return (unsigned short)(r >> 16);
}
__device__ __forceinline__ float bf16_tof(unsigned short u) {
  return __uint_as_float(((unsigned)u) << 16);
}

__device__ __forceinline__ uint cvt_pk_bf16(float a, float b) {
  uint r;
  asm("v_cvt_pk_bf16_f32 %0, %1, %2" : "=v"(r) : "v"(a), "v"(b));
  return r;
}

// LDS-only barrier: order LDS ops across the barrier WITHOUT draining vmcnt.
__device__ __forceinline__ void lds_barrier() {
  asm volatile("s_waitcnt lgkmcnt(0)" ::: "memory");
  __builtin_amdgcn_s_barrier();
}

// ---------------------------------------------------------------------------
// splitx: x [8192][512] fp32 -> hi/lo bf16 in MFMA A-staging layout.
// ---------------------------------------------------------------------------
__global__ __launch_bounds__(256) void splitx_kernel(
    const float* __restrict__ X, unsigned short* __restrict__ Th,
    unsigned short* __restrict__ Tl) {
  const size_t tid = (size_t)blockIdx.x * 256 + threadIdx.x;  // 16*8192
  const int kt = (int)(tid >> 13);
  const int row = (int)(tid & 8191);
  const float* src = X + (size_t)row * 512 + kt * 32;
  #pragma unroll
  for (int kc = 0; kc < 4; ++kc) {
    ushort8_t hi, lo;
    #pragma unroll
    for (int e = 0; e < 8; ++e) {
      const float v = src[kc * 8 + e];
      const unsigned short h = bf16_hi(v);
      hi[e] = h;
      lo[e] = bf16_hi(v - bf16_tof(h));
    }
    const size_t o = ((size_t)(kt * 4 + kc) * 8192 + row) * 8;
    *reinterpret_cast<ushort8_t*>(&Th[o]) = hi;
    *reinterpret_cast<ushort8_t*>(&Tl[o]) = lo;
  }
}

// ---------------------------------------------------------------------------
// splitw: W0 [512][256] fp32 -> hi/lo bf16 in B-staging layout.
// ---------------------------------------------------------------------------
__global__ __launch_bounds__(256) void splitw_kernel(
    const float* __restrict__ W, unsigned short* __restrict__ Th,
    unsigned short* __restrict__ Tl) {
  const int tid = blockIdx.x * 256 + threadIdx.x;   // 64*256
  const int kb = tid >> 8;
  const int col = tid & 255;
  ushort8_t hi, lo;
  #pragma unroll
  for (int e = 0; e < 8; ++e) {
    const float v = W[(size_t)(kb * 8 + e) * 256 + col];
    const unsigned short h = bf16_hi(v);
    hi[e] = h;
    lo[e] = bf16_hi(v - bf16_tof(h));
  }
  const size_t o = ((size_t)kb * 256 + col) * 8;
  *reinterpret_cast<ushort8_t*>(&Th[o]) = hi;
  *reinterpret_cast<ushort8_t*>(&Tl[o]) = lo;
}

// ---------------------------------------------------------------------------
// gemm1_mfma: h0 = x @ W0 via bf16x3 MFMA (32x32x16), 256 blocks x 512 thr.
// Epilogue FUSES split1: writes h0 (for sn1) AND Th0/Tl0 in split layout.
// ---------------------------------------------------------------------------
__global__ __launch_bounds__(512) void gemm1_mfma_kernel(
    const unsigned short* __restrict__ Axh, const unsigned short* __restrict__ Axl,
    const unsigned short* __restrict__ Bwh, const unsigned short* __restrict__ Bwl,
    float* __restrict__ C, unsigned short* __restrict__ Th,
    unsigned short* __restrict__ Tl) {
  const int t = threadIdx.x;
  const int lane = t & 63;
  const int cf = t >> 6;
  const int i0 = blockIdx.x * 32;
  const int col = cf * 32 + (lane & 31);
  const size_t abase = ((size_t)(lane >> 5) * 8192 + i0 + (lane & 31)) * 8;
  const size_t bbase = ((size_t)(lane >> 5) * 256 + col) * 8;

  f32x16 acc;
  #pragma unroll
  for (int i = 0; i < 16; ++i) acc[i] = 0.f;

  #pragma unroll 2
  for (int kt = 0; kt < 16; ++kt) {
    const size_t at = (size_t)kt * 4 * 8192 * 8;
    const size_t bt = (size_t)kt * 4 * 256 * 8;
    #pragma unroll
    for (int h = 0; h < 2; ++h) {
      const size_t ao = at + (size_t)h * 2 * 8192 * 8 + abase;
      const size_t bo = bt + (size_t)h * 2 * 256 * 8 + bbase;
      const bf16x8 ah = *reinterpret_cast<const bf16x8*>(Axh + ao);
      const bf16x8 al = *reinterpret_cast<const bf16x8*>(Axl + ao);
      const bf16x8 bh = *reinterpret_cast<const bf16x8*>(Bwh + bo);
      const bf16x8 bl = *reinterpret_cast<const bf16x8*>(Bwl + bo);
      acc = __builtin_amdgcn_mfma_f32_32x32x16_bf16(al, bh, acc, 0, 0, 0);
      acc = __builtin_amdgcn_mfma_f32_32x32x16_bf16(ah, bl, acc, 0, 0, 0);
      acc = __builtin_amdgcn_mfma_f32_32x32x16_bf16(ah, bh, acc, 0, 0, 0);
    }
  }

  #pragma unroll
  for (int reg = 0; reg < 16; ++reg) {
    const int row = (reg & 3) + 8 * (reg >> 2) + 4 * (lane >> 5);
    const float v = acc[reg];
    C[(size_t)(i0 + row) * 256 + col] = v;
    const unsigned short h = bf16_hi(v);
    const unsigned short l = bf16_hi(v - bf16_tof(h));
    const size_t o = ((size_t)(blockIdx.x * 4 + (row >> 3)) * 256 + col) * 8 + (row & 7);
    Th[o] = h;
    Tl[o] = l;
  }
}

// ---------------------------------------------------------------------------
// s[i] = h[i].a_self ; n[i] = h[i].a_neigh   (one wave per row) — layer 1
// ---------------------------------------------------------------------------
template<int FOUT>
__global__ __launch_bounds__(256) void sn_kernel(
    const float* __restrict__ H, const float* __restrict__ a_self,
    const float* __restrict__ a_neigh, float* __restrict__ s, float* __restrict__ n) {
  const int wave = threadIdx.x >> 6;
  const int lane = threadIdx.x & 63;
  const int row = blockIdx.x * 4 + wave;
  float ds = 0.f, dn = 0.f;
  #pragma unroll
  for (int c = lane; c < FOUT; c += 64) {
    const float h = H[(size_t)row * FOUT + c];
    ds += h * a_self[c];
    dn += h * a_neigh[c];
  }
  #pragma unroll
  for (int off = 32; off > 0; off >>= 1) {
    ds += __shfl_down(ds, off);
    dn += __shfl_down(dn, off);
  }
  if (lane == 0) { s[row] = ds; n[row] = dn; }
}

// ---------------------------------------------------------------------------
// plsum: il[row] = 1/(pL[0][row] + pL[1][row])
// ---------------------------------------------------------------------------
__global__ __launch_bounds__(256) void plsum_kernel(
    const float* __restrict__ pL, float* __restrict__ il) {
  const int i = blockIdx.x * 256 + threadIdx.x;
  il[i] = 1.0f / (pL[i] + pL[8192 + i]);
}

// ---------------------------------------------------------------------------
// combine2: out = elu((pO[0]+pO[1]) / (pL[0]+pL[1]))   (final output)
// ---------------------------------------------------------------------------
template<int F>
__global__ __launch_bounds__(256) void combine_kernel(
    const float* __restrict__ pO, const float* __restrict__ pL, float* __restrict__ out) {
  const size_t q = (size_t)blockIdx.x * 256 + threadIdx.x;
  const size_t base = q * 4;
  const int row = (int)(base / F);
  const float4 a = *reinterpret_cast<const float4*>(pO + base);
  const float4 b = *reinterpret_cast<const float4*>(pO + (size_t)8192 * F + base);
  const float il = 1.0f / (pL[row] + pL[8192 + row]);
  float4 o;
  o.x = eluf((a.x + b.x) * il);
  o.y = eluf((a.y + b.y) * il);
  o.z = eluf((a.z + b.z) * il);
  o.w = eluf((a.w + b.w) * il);
  *reinterpret_cast<float4*>(out + base) = o;
}

// ---------------------------------------------------------------------------
// gemm2_fused: h1 = elu((pO1_0+pO1_1)*il1) @ W1; epilogue fuses sn2 + split2.
// ---------------------------------------------------------------------------
__global__ __launch_bounds__(256) void gemm2_fused_kernel(
    const float* __restrict__ pO1, const float* __restrict__ il1,
    const float* __restrict__ W, const float* __restrict__ a_self,
    const float* __restrict__ a_neigh, unsigned short* __restrict__ Th,
    unsigned short* __restrict__ Tl, float* __restrict__ s1,
    float* __restrict__ n1) {
  constexpr int K = 256, NOUT = 64, BM = 64, BK = 16;
  const size_t seg = (size_t)8192 * 256;
  __shared__ __align__(16) float As[BK][BM + 4];
  __shared__ __align__(16) float Ws[BK][NOUT];
  __shared__ float red_s[64][17];
  __shared__ float red_n[64][17];
  const int t = threadIdx.x;
  const int i0 = blockIdx.x * BM;
  const int tr = t >> 4;
  const int tc = t & 15;
  const int lr = t >> 2;
  const int lk = (t & 3) * 4;
  const int wk = t >> 4;
  const int wc = (t & 15) * 4;
  const float ilr = il1[i0 + lr];
  float acc[4][4] = {};
  for (int k0 = 0; k0 < K; k0 += BK) {
    const size_t aoff = (size_t)(i0 + lr) * 256 + k0 + lk;
    const float4 p0 = *reinterpret_cast<const float4*>(&pO1[aoff]);
    const float4 p1 = *reinterpret_cast<const float4*>(&pO1[seg + aoff]);
    As[lk + 0][lr] = eluf((p0.x + p1.x) * ilr);
    As[lk + 1][lr] = eluf((p0.y + p1.y) * ilr);
    As[lk + 2][lr] = eluf((p0.z + p1.z) * ilr);
    As[lk + 3][lr] = eluf((p0.w + p1.w) * ilr);
    *reinterpret_cast<float4*>(&Ws[wk][wc]) =
        *reinterpret_cast<const float4*>(&W[(size_t)(k0 + wk) * NOUT + wc]);
    __syncthreads();
    #pragma unroll
    for (int kk = 0; kk < BK; ++kk) {
      const float4 av = *reinterpret_cast<const float4*>(&As[kk][4 * tr]);
      const float4 wv = *reinterpret_cast<const float4*>(&Ws[kk][4 * tc]);
      const float a[4] = {av.x, av.y, av.z, av.w};
      const float w[4] = {wv.x, wv.y, wv.z, wv.w};
      #pragma unroll
      for (int i = 0; i < 4; ++i)
        #pragma unroll
        for (int j = 0; j < 4; ++j) acc[i][j] += a[i] * w[j];
    }
    __syncthreads();
  }
  float asv[4], anv[4];
  #pragma unroll
  for (int j = 0; j < 4; ++j) {
    asv[j] = a_self[4 * tc + j];
    anv[j] = a_neigh[4 * tc + j];
  }
  #pragma unroll
  for (int i = 0; i < 4; ++i) {
    float ps = 0.f, pn = 0.f;
    #pragma unroll
    for (int j = 0; j < 4; ++j) { ps += acc[i][j] * asv[j]; pn += acc[i][j] * anv[j]; }
    red_s[4 * tr + i][tc] = ps;
    red_n[4 * tr + i][tc] = pn;
  }
  #pragma unroll
  for (int i = 0; i < 4; ++i) {
    const int row = 4 * tr + i;
    const int tile = 2 * blockIdx.x + (row >> 5);
    const int kc = (row >> 3) & 3;
    const int e = row & 7;
    #pragma unroll
    for (int j = 0; j < 4; ++j) {
      const int col = 4 * tc + j;
      const float v = acc[i][j];
      const unsigned short h = bf16_hi(v);
      const unsigned short l = bf16_hi(v - bf16_tof(h));
      const size_t o = ((size_t)(tile * 4 + kc) * 64 + col) * 8 + e;
      Th[o] = h;
      Tl[o] = l;
    }
  }
  __syncthreads();
  if (t < 64) {
    float ss = 0.f, nn = 0.f;
    #pragma unroll
    for (int q = 0; q < 16; ++q) { ss += red_s[t][q]; nn += red_n[t][q]; }
    s1[i0 + t] = ss;
    n1[i0 + t] = nn;
  }
}

// ---------------------------------------------------------------------------
// Layer-1 fused attention + mask production. Grid (128,2): 64 rows x j-half.
// Reads adj DIRECTLY (int2 per rowgroup, 1-tile-deep consume-then-refill) and
// writes the bitmask Bm for attn2 via a 16-lane OR-reduce (one u32/16 lanes).
// Mask registers replaced by adj registers: net-0 VGPR delta vs R16.
// ---------------------------------------------------------------------------
__global__ __launch_bounds__(1024, 4) void attn1_kernel(
    const float* __restrict__ Mm, const int* __restrict__ adj,
    const float* __restrict__ sv, const float* __restrict__ nv,
    const unsigned short* __restrict__ Th, const unsigned short* __restrict__ Tl,
    float* __restrict__ pO, float* __restrict__ pL, uint* __restrict__ BmOut) {
  constexpr int F = 256, NT = 4096 / 64;
  __shared__ __align__(16) uint Pa[2][2][2][8 * 132];  // [buf][part][rg][g*132+r*4+q]
  __shared__ __align__(16) float nvs[8192];            // [0..4095]=nv half; full=scratch
  __shared__ float l_lds[64];

  const int t = threadIdx.x;
  const int lane = t & 63;
  const int w = t >> 6;
  const int cf = w & 7;
  const int ks = w >> 3;
  const int r = t >> 5;              // score row 0..31 (per rowgroup)
  const int p2 = t & 31;             // col pair 2p2,2p2+1 (of 64)
  const int i0 = blockIdx.x * 64;
  const int jh = blockIdx.y;
  const size_t jbase = (size_t)jh * 4096;
  const int jt = jh * 128;           // tile32 base

  reinterpret_cast<float4*>(nvs)[t] = reinterpret_cast<const float4*>(nv + jbase)[t];

  const float svrA = sv[i0 + r];
  const float svrB = sv[i0 + 32 + r];
  const size_t mrowA = (size_t)(i0 + r) * NN + jbase;
  const size_t mrowB = mrowA + (size_t)32 * NN;
  const size_t bmrowA = (size_t)(i0 + r) * (NN / 32) + jh * 128;
  const size_t bmrowB = bmrowA + (size_t)32 * (NN / 32);
  const int col = cf * 32 + (lane & 31);
  const size_t bo0 = ((size_t)(lane >> 5) * F + col) * 8;
  const int pidx = (p2 >> 2) * 132 + r * 4 + (p2 & 3);
  const int aidx = (ks * 4 + (lane >> 5)) * 132 + (lane & 31) * 4;
  const int mshift = 2 * (p2 & 15);

  float2 MA_e = *reinterpret_cast<const float2*>(&Mm[mrowA + 2 * p2]);
  float2 MA_o = *reinterpret_cast<const float2*>(&Mm[mrowA + 64 + 2 * p2]);
  float2 MB_e = *reinterpret_cast<const float2*>(&Mm[mrowB + 2 * p2]);
  float2 MB_o = *reinterpret_cast<const float2*>(&Mm[mrowB + 64 + 2 * p2]);
  int2 aA = *reinterpret_cast<const int2*>(&adj[mrowA + 2 * p2]);   // tile 0
  int2 aB = *reinterpret_cast<const int2*>(&adj[mrowB + 2 * p2]);
  const size_t tb0 = (size_t)(jt + ks) * 8192;
  bf16x8 bh0_e = *reinterpret_cast<const bf16x8*>(Th + tb0 + bo0);
  bf16x8 bl0_e = *reinterpret_cast<const bf16x8*>(Tl + tb0 + bo0);
  bf16x8 bh1_e = *reinterpret_cast<const bf16x8*>(Th + tb0 + bo0 + 4096);
  bf16x8 bl1_e = *reinterpret_cast<const bf16x8*>(Tl + tb0 + bo0 + 4096);
  bf16x8 bh0_o, bl0_o, bh1_o, bl1_o;

  float rsumA = 0.f, rsumB = 0.f;
  f32x16 accA, accB;
  #pragma unroll
  for (int i = 0; i < 16; ++i) { accA[i] = 0.f; accB[i] = 0.f; }

  __syncthreads();   // nvs staged

  float2 nv_e = *reinterpret_cast<const float2*>(&nvs[2 * p2]);
  float2 nv_o = *reinterpret_cast<const float2*>(&nvs[64 + 2 * p2]);

#define STEP1(TJ, MCA, MCB, NVC, BH0C, BL0C, BH1C, BL1C, BH0N, BL0N, BH1N, BL1N)  \
  {                                                                               \
    const int t_j = (TJ);                                                         \
    const int jb = (t_j + 1 < NT) ? t_j + 1 : 0;                                  \
    const size_t tb = (size_t)(jt + 2 * jb + ks) * 8192;                          \
    BH0N = *reinterpret_cast<const bf16x8*>(Th + tb + bo0);                       \
    BL0N = *reinterpret_cast<const bf16x8*>(Tl + tb + bo0);                       \
    BH1N = *reinterpret_cast<const bf16x8*>(Th + tb + bo0 + 4096);                \
    BL1N = *reinterpret_cast<const bf16x8*>(Tl + tb + bo0 + 4096);                \
    float e0 = (svrA + NVC.x) * MCA.x; e0 = fmaxf(e0, 0.2f * e0); e0 = fminf(e0, 70.f); \
    float e1 = (svrA + NVC.y) * MCA.y; e1 = fmaxf(e1, 0.2f * e1); e1 = fminf(e1, 70.f); \
    float e2 = (svrB + NVC.x) * MCB.x; e2 = fmaxf(e2, 0.2f * e2); e2 = fminf(e2, 70.f); \
    float e3 = (svrB + NVC.y) * MCB.y; e3 = fmaxf(e3, 0.2f * e3); e3 = fminf(e3, 70.f); \
    const float pA0 = (aA.x > 0) ? __expf(e0) : 0.f;                              \
    const float pA1 = (aA.y > 0) ? __expf(e1) : 0.f;                              \
    const float pB0 = (aB.x > 0) ? __expf(e2) : 0.f;                              \
    const float pB1 = (aB.y > 0) ? __expf(e3) : 0.f;                              \
    /* Bm production: 16-lane OR-reduce, one u32 store per 16 lanes */            \
    uint wA = ((aA.x > 0 ? 1u : 0u) | (aA.y > 0 ? 2u : 0u)) << mshift;            \
    uint wB = ((aB.x > 0 ? 1u : 0u) | (aB.y > 0 ? 2u : 0u)) << mshift;            \
    wA |= __shfl_xor(wA, 1); wB |= __shfl_xor(wB, 1);                             \
    wA |= __shfl_xor(wA, 2); wB |= __shfl_xor(wB, 2);                             \
    wA |= __shfl_xor(wA, 4); wB |= __shfl_xor(wB, 4);                             \
    wA |= __shfl_xor(wA, 8); wB |= __shfl_xor(wB, 8);                             \
    if ((p2 & 15) == 0) {                                                         \
      BmOut[bmrowA + t_j * 2 + (p2 >> 4)] = wA;                                   \
      BmOut[bmrowB + t_j * 2 + (p2 >> 4)] = wB;                                   \
    }                                                                             \
    rsumA += pA0 + pA1; rsumB += pB0 + pB1;                                       \
    const int jm = (t_j + 2 < NT) ? t_j + 2 : 0;                                  \
    const int jm1 = (t_j + 1 < NT) ? t_j + 1 : 0;                                 \
    MCA = *reinterpret_cast<const float2*>(&Mm[mrowA + (size_t)jm * 64 + 2 * p2]); \
    MCB = *reinterpret_cast<const float2*>(&Mm[mrowB + (size_t)jm * 64 + 2 * p2]); \
    aA = *reinterpret_cast<const int2*>(&adj[mrowA + (size_t)jm1 * 64 + 2 * p2]); \
    aB = *reinterpret_cast<const int2*>(&adj[mrowB + (size_t)jm1 * 64 + 2 * p2]); \
    NVC = *reinterpret_cast<const float2*>(&nvs[jm * 64 + 2 * p2]);               \
    const uint hwA = cvt_pk_bf16(pA0, pA1);                                       \
    const uint lwA = cvt_pk_bf16(pA0 - __uint_as_float(hwA << 16),                \
                                 pA1 - __uint_as_float(hwA & 0xffff0000u));       \
    const uint hwB = cvt_pk_bf16(pB0, pB1);                                       \
    const uint lwB = cvt_pk_bf16(pB0 - __uint_as_float(hwB << 16),                \
                                 pB1 - __uint_as_float(hwB & 0xffff0000u));       \
    Pa[t_j & 1][0][0][pidx] = hwA;                                                \
    Pa[t_j & 1][1][0][pidx] = lwA;                                                \
    Pa[t_j & 1][0][1][pidx] = hwB;                                                \
    Pa[t_j & 1][1][1][pidx] = lwB;                                                \
    lds_barrier();                                                                \
    const bf16x8 ahA0 = *reinterpret_cast<const bf16x8*>(&Pa[t_j & 1][0][0][aidx]);       \
    const bf16x8 alA0 = *reinterpret_cast<const bf16x8*>(&Pa[t_j & 1][1][0][aidx]);       \
    const bf16x8 ahA1 = *reinterpret_cast<const bf16x8*>(&Pa[t_j & 1][0][0][aidx + 264]); \
    const bf16x8 alA1 = *reinterpret_cast<const bf16x8*>(&Pa[t_j & 1][1][0][aidx + 264]); \
    const bf16x8 ahB0 = *reinterpret_cast<const bf16x8*>(&Pa[t_j & 1][0][1][aidx]);       \
    const bf16x8 alB0 = *reinterpret_cast<const bf16x8*>(&Pa[t_j & 1][1][1][aidx]);       \
    const bf16x8 ahB1 = *reinterpret_cast<const bf16x8*>(&Pa[t_j & 1][0][1][aidx + 264]); \
    const bf16x8 alB1 = *reinterpret_cast<const bf16x8*>(&Pa[t_j & 1][1][1][aidx + 264]); \
    accA = __builtin_amdgcn_mfma_f32_32x32x16_bf16(alA0, BH0C, accA, 0, 0, 0);    \
    accB = __builtin_amdgcn_mfma_f32_32x32x16_bf16(alB0, BH0C, accB, 0, 0, 0);    \
    accA = __builtin_amdgcn_mfma_f32_32x32x16_bf16(ahA0, BL0C, accA, 0, 0, 0);    \
    accB = __builtin_amdgcn_mfma_f32_32x32x16_bf16(ahB0, BL0C, accB, 0, 0, 0);    \
    accA = __builtin_amdgcn_mfma_f32_32x32x16_bf16(ahA0, BH0C, accA, 0, 0, 0);    \
    accB = __builtin_amdgcn_mfma_f32_32x32x16_bf16(ahB0, BH0C, accB, 0, 0, 0);    \
    accA = __builtin_amdgcn_mfma_f32_32x32x16_bf16(alA1, BH1C, accA, 0, 0, 0);    \
    accB = __builtin_amdgcn_mfma_f32_32x32x16_bf16(alB1, BH1C, accB, 0, 0, 0);    \
    accA = __builtin_amdgcn_mfma_f32_32x32x16_bf16(ahA1, BL1C, accA, 0, 0, 0);    \
    accB = __builtin_amdgcn_mfma_f32_32x32x16_bf16(ahB1, BL1C, accB, 0, 0, 0);    \
    accA = __builtin_amdgcn_mfma_f32_32x32x16_bf16(ahA1, BH1C, accA, 0, 0, 0);    \
    accB = __builtin_amdgcn_mfma_f32_32x32x16_bf16(ahB1, BH1C, accB, 0, 0, 0);    \
  }

  for (int tj = 0; tj < NT; tj += 2) {
    STEP1(tj,     MA_e, MB_e, nv_e, bh0_e, bl0_e, bh1_e, bl1_e, bh0_o, bl0_o, bh1_o, bl1_o)
    STEP1(tj + 1, MA_o, MB_o, nv_o, bh0_o, bl0_o, bh1_o, bl1_o, bh0_e, bl0_e, bh1_e, bl1_e)
  }
#undef STEP1

  #pragma unroll
  for (int off = 1; off < 32; off <<= 1) {
    rsumA += __shfl_xor(rsumA, off);
    rsumB += __shfl_xor(rsumB, off);
  }
  if (p2 == 0) { l_lds[r] = rsumA; l_lds[32 + r] = rsumB; }
  __syncthreads();
  if (t < 64) pL[(size_t)jh * 8192 + i0 + t] = l_lds[t];

  // k-half reduce via LDS scratch (reuse nvs, 32KB), rowgroup A then B.
  float* scratch = nvs;
  if (ks == 1) {
    #pragma unroll
    for (int reg = 0; reg < 16; ++reg) scratch[cf * 1024 + reg * 64 + lane] = accA[reg];
  }
  __syncthreads();
  if (ks == 0) {
    #pragma unroll
    for (int reg = 0; reg < 16; ++reg) {
      const int row = (reg & 3) + 8 * (reg >> 2) + 4 * (lane >> 5);
      pO[(size_t)jh * 8192 * F + (size_t)(i0 + row) * F + col] =
          accA[reg] + scratch[cf * 1024 + reg * 64 + lane];
    }
  }
  __syncthreads();
  if (ks == 1) {
    #pragma unroll
    for (int reg = 0; reg < 16; ++reg) scratch[cf * 1024 + reg * 64 + lane] = accB[reg];
  }
  __syncthreads();
  if (ks == 0) {
    #pragma unroll
    for (int reg = 0; reg < 16; ++reg) {
      const int row = (reg & 3) + 8 * (reg >> 2) + 4 * (lane >> 5);
      pO[(size_t)jh * 8192 * F + (size_t)(i0 + 32 + row) * F + col] =
          accB[reg] + scratch[cf * 1024 + reg * 64 + lane];
    }
  }
}

// ---------------------------------------------------------------------------
// Layer-2 fused attention. Grid (128,2): 64 rows x j-half, 1024 thr.
// ---------------------------------------------------------------------------
__global__ __launch_bounds__(1024, 4) void attn2_kernel(
    const float* __restrict__ Mm, const uint* __restrict__ Bm,
    const float* __restrict__ sv, const float* __restrict__ nv,
    const unsigned short* __restrict__ Th, const unsigned short* __restrict__ Tl,
    float* __restrict__ pO, float* __restrict__ pL) {
  constexpr int F = 64, NT = 4096 / 64;
  __shared__ __align__(16) uint Pa[2][2][2][8 * 132];
  __shared__ __align__(16) float nvs[4096];
  __shared__ float l_lds[64];

  const int t = threadIdx.x;
  const int lane = t & 63;
  const int w = t >> 6;
  const int rb = w & 1;
  const int cf = (w >> 1) & 3;
  const int ks = w >> 3;
  const int r = t >> 5;
  const int p2 = t & 31;
  const int i0 = blockIdx.x * 64;
  const int jh = blockIdx.y;
  const size_t jbase = (size_t)jh * 4096;
  const int jt = jh * 128;

  reinterpret_cast<float4*>(nvs)[t] = reinterpret_cast<const float4*>(nv + jbase)[t];

  const float svrA = sv[i0 + r];
  const float svrB = sv[i0 + 32 + r];
  const size_t mrowA = (size_t)(i0 + r) * NN + jbase;
  const size_t mrowB = mrowA + (size_t)32 * NN;
  const uint* mkrowA = Bm + (size_t)(i0 + r) * (NN / 32) + jh * 128;
  const uint* mkrowB = mkrowA + (size_t)32 * (NN / 32);
  const int col = cf * 16 + (lane & 15);
  const size_t bo2 = ((size_t)(lane >> 4) * F + col) * 8;
  const int pidx = (p2 >> 2) * 132 + r * 4 + (p2 & 3);
  const int aidx = (ks * 4 + (lane >> 4)) * 132 + (rb * 16 + (lane & 15)) * 4;

  float2 MA_e = *reinterpret_cast<const float2*>(&Mm[mrowA + 2 * p2]);
  float2 MA_o = *reinterpret_cast<const float2*>(&Mm[mrowA + 64 + 2 * p2]);
  float2 MB_e = *reinterpret_cast<const float2*>(&Mm[mrowB + 2 * p2]);
  float2 MB_o = *reinterpret_cast<const float2*>(&Mm[mrowB + 64 + 2 * p2]);
  uint mkA_e = mkrowA[p2 >> 4];
  uint mkA_o = mkrowA[2 + (p2 >> 4)];
  uint mkB_e = mkrowB[p2 >> 4];
  uint mkB_o = mkrowB[2 + (p2 >> 4)];
  const size_t tb0 = (size_t)(jt + ks) * 2048;
  bf16x8 bh_e = *reinterpret_cast<const bf16x8*>(Th + tb0 + bo2);
  bf16x8 bl_e = *reinterpret_cast<const bf16x8*>(Tl + tb0 + bo2);
  bf16x8 bh_o, bl_o;

  float rsumA = 0.f, rsumB = 0.f;
  f32x4 accA = {0.f, 0.f, 0.f, 0.f}, accA2 = {0.f, 0.f, 0.f, 0.f};
  f32x4 accB = {0.f, 0.f, 0.f, 0.f}, accB2 = {0.f, 0.f, 0.f, 0.f};

  __syncthreads();   // nvs staged

  float2 nv_e = *reinterpret_cast<const float2*>(&nvs[2 * p2]);
  float2 nv_o = *reinterpret_cast<const float2*>(&nvs[64 + 2 * p2]);

#define STEP2(TJ, MCA, MKA, MCB, MKB, NVC, BHC, BLC, BHN, BLN)                    \
  {                                                                               \
    const int t_j = (TJ);                                                         \
    const int jb = (t_j + 1 < NT) ? t_j + 1 : 0;                                  \
    const size_t tb = (size_t)(jt + 2 * jb + ks) * 2048;                          \
    BHN = *reinterpret_cast<const bf16x8*>(Th + tb + bo2);                        \
    BLN = *reinterpret_cast<const bf16x8*>(Tl + tb + bo2);                        \
    float e0 = (svrA + NVC.x) * MCA.x; e0 = fmaxf(e0, 0.2f * e0); e0 = fminf(e0, 70.f); \
    float e1 = (svrA + NVC.y) * MCA.y; e1 = fmaxf(e1, 0.2f * e1); e1 = fminf(e1, 70.f); \
    float e2 = (svrB + NVC.x) * MCB.x; e2 = fmaxf(e2, 0.2f * e2); e2 = fminf(e2, 70.f); \
    float e3 = (svrB + NVC.y) * MCB.y; e3 = fmaxf(e3, 0.2f * e3); e3 = fminf(e3, 70.f); \
    const float pA0 = ((MKA >> (2 * (p2 & 15))) & 1u) ? __expf(e0) : 0.f;         \
    const float pA1 = ((MKA >> (2 * (p2 & 15) + 1)) & 1u) ? __expf(e1) : 0.f;     \
    const float pB0 = ((MKB >> (2 * (p2 & 15))) & 1u) ? __expf(e2) : 0.f;         \
    const float pB1 = ((MKB >> (2 * (p2 & 15) + 1)) & 1u) ? __expf(e3) : 0.f;     \
    rsumA += pA0 + pA1; rsumB += pB0 + pB1;                                       \
    const int jm = (t_j + 2 < NT) ? t_j + 2 : 0;                                  \
    MCA = *reinterpret_cast<const float2*>(&Mm[mrowA + (size_t)jm * 64 + 2 * p2]); \
    MKA = mkrowA[jm * 2 + (p2 >> 4)];                                             \
    MCB = *reinterpret_cast<const float2*>(&Mm[mrowB + (size_t)jm * 64 + 2 * p2]); \
    MKB = mkrowB[jm * 2 + (p2 >> 4)];                                             \
    NVC = *reinterpret_cast<const float2*>(&nvs[jm * 64 + 2 * p2]);               \
    const uint hwA = cvt_pk_bf16(pA0, pA1);                                       \
    const uint lwA = cvt_pk_bf16(pA0 - __uint_as_float(hwA << 16),                \
                                 pA1 - __uint_as_float(hwA & 0xffff0000u));       \
    const uint hwB = cvt_pk_bf16(pB0, pB1);                                       \
    const uint lwB = cvt_pk_bf16(pB0 - __uint_as_float(hwB << 16),                \
                                 pB1 - __uint_as_float(hwB & 0xffff0000u));       \
    Pa[t_j & 1][0][0][pidx] = hwA;                                                \
    Pa[t_j & 1][1][0][pidx] = lwA;                                                \
    Pa[t_j & 1][0][1][pidx] = hwB;                                                \
    Pa[t_j & 1][1][1][pidx] = lwB;                                                \
    lds_barrier();                                                                \
    const bf16x8 ahA = *reinterpret_cast<const bf16x8*>(&Pa[t_j & 1][0][0][aidx]); \
    const bf16x8 alA = *reinterpret_cast<const bf16x8*>(&Pa[t_j & 1][1][0][aidx]); \
    const bf16x8 ahB = *reinterpret_cast<const bf16x8*>(&Pa[t_j & 1][0][1][aidx]); \
    const bf16x8 alB = *reinterpret_cast<const bf16x8*>(&Pa[t_j & 1][1][1][aidx]); \
    accA  = __builtin_amdgcn_mfma_f32_16x16x32_bf16(alA, BHC, accA, 0, 0, 0);     \
    accB  = __builtin_amdgcn_mfma_f32_16x16x32_bf16(alB, BHC, accB, 0, 0, 0);     \
    accA2 = __builtin_amdgcn_mfma_f32_16x16x32_bf16(ahA, BLC, accA2, 0, 0, 0);    \
    accB2 = __builtin_amdgcn_mfma_f32_16x16x32_bf16(ahB, BLC, accB2, 0, 0, 0);    \
    accA  = __builtin_amdgcn_mfma_f32_16x16x32_bf16(ahA, BHC, accA, 0, 0, 0);     \
    accB  = __builtin_amdgcn_mfma_f32_16x16x32_bf16(ahB, BHC, accB, 0, 0, 0);     \
  }

  for (int tj = 0; tj < NT; tj += 2) {
    STEP2(tj,     MA_e, mkA_e, MB_e, mkB_e, nv_e, bh_e, bl_e, bh_o, bl_o)
    STEP2(tj + 1, MA_o, mkA_o, MB_o, mkB_o, nv_o, bh_o, bl_o, bh_e, bl_e)
  }
#undef STEP2

  #pragma unroll
  for (int off = 1; off < 32; off <<= 1) {
    rsumA += __shfl_xor(rsumA, off);
    rsumB += __shfl_xor(rsumB, off);
  }
  if (p2 == 0) { l_lds[r] = rsumA; l_lds[32 + r] = rsumB; }
  __syncthreads();
  if (t < 64) pL[(size_t)jh * 8192 + i0 + t] = l_lds[t];

  float* scratch = nvs;
  if (ks == 1) {
    #pragma unroll
    for (int reg = 0; reg < 4; ++reg)
      scratch[(w & 7) * 256 + reg * 64 + lane] = accA[reg] + accA2[reg];
  }
  __syncthreads();
  if (ks == 0) {
    #pragma unroll
    for (int reg = 0; reg < 4; ++reg) {
      const int row = rb * 16 + (lane >> 4) * 4 + reg;
      pO[(size_t)jh * 8192 * F + (size_t)(i0 + row) * F + col] =
          accA[reg] + accA2[reg] + scratch[(w & 7) * 256 + reg * 64 + lane];
    }
  }
  __syncthreads();
  if (ks == 1) {
    #pragma unroll
    for (int reg = 0; reg < 4; ++reg)
      scratch[(w & 7) * 256 + reg * 64 + lane] = accB[reg] + accB2[reg];
  }
  __syncthreads();
  if (ks == 0) {
    #pragma unroll
    for (int reg = 0; reg < 4; ++reg) {
      const int row = rb * 16 + (lane >> 4) * 4 + reg;
      pO[(size_t)jh * 8192 * F + (size_t)(i0 + 32 + row) * F + col] =
          accB[reg] + accB2[reg] + scratch[(w & 7) * 256 + reg * 64 + lane];
    }
  }
}

// ---------------------------------------------------------------------------
extern "C" void kernel_launch(void* const* d_in, const int* in_sizes, int n_in,
                              void* d_out, int out_size, void* d_ws, size_t ws_size,
                              hipStream_t stream) {
  const float* x   = (const float*)d_in[0];
  const int*   adj = (const int*)  d_in[1];
  const float* Mm  = (const float*)d_in[2];
  const float* W0  = (const float*)d_in[3];
  const float* as0 = (const float*)d_in[4];
  const float* an0 = (const float*)d_in[5];
  const float* W1  = (const float*)d_in[6];
  const float* as1 = (const float*)d_in[7];
  const float* an1 = (const float*)d_in[8];
  float* out = (float*)d_out;

  char* ws = (char*)d_ws;
  const size_t MB = 1048576;
  const size_t KB = 1024;
  float* h0  = (float*)(ws);                              // 8 MB (dead after sn1)
  uint*  Bm  = (uint*) (ws);                              // 8 MB (written by attn1)
  unsigned short* Th0 = (unsigned short*)(ws + 18 * MB);  // 4 MB
  unsigned short* Tl0 = (unsigned short*)(ws + 22 * MB);  // 4 MB
  unsigned short* Th1 = (unsigned short*)(ws + 26 * MB);  // 1 MB
  unsigned short* Tl1 = (unsigned short*)(ws + 27 * MB);  // 1 MB
  float* s0  = (float*)(ws + 28 * MB);
  float* n0  = (float*)(ws + 28 * MB + 32 * KB);
  float* s1  = (float*)(ws + 28 * MB + 64 * KB);
  float* n1  = (float*)(ws + 28 * MB + 96 * KB);
  float* pL1 = (float*)(ws + 28 * MB + 128 * KB);         // 64 KB [2][8192]
  float* pL2 = (float*)(ws + 28 * MB + 192 * KB);         // 64 KB
  float* il1 = (float*)(ws + 28 * MB + 256 * KB);         // 32 KB
  float* pO1 = (float*)(ws + 29 * MB);                    // 16 MB [2][8192][256]
  float* pO2 = (float*)(ws + 29 * MB);                    // 4 MB  [2][8192][64] (pO1 dead)
  unsigned short* Txh = (unsigned short*)(ws + 64 * MB);  // 8 MB (x split hi)
  unsigned short* Txl = (unsigned short*)(ws + 72 * MB);  // 8 MB (x split lo)
  unsigned short* Twh = (unsigned short*)(ws + 80 * MB);  // 256 KB (W0 split hi)
  unsigned short* Twl = (unsigned short*)(ws + 81 * MB);  // 256 KB (W0 split lo)

  // ---- layer 1 ----
  splitx_kernel<<<dim3(512), dim3(256), 0, stream>>>(x, Txh, Txl);
  splitw_kernel<<<dim3(64), dim3(256), 0, stream>>>(W0, Twh, Twl);
  gemm1_mfma_kernel<<<dim3(256), dim3(512), 0, stream>>>(Txh, Txl, Twh, Twl, h0, Th0, Tl0);
  sn_kernel<256><<<dim3(2048), dim3(256), 0, stream>>>(h0, as0, an0, s0, n0);
  // attn1 reads adj directly and PRODUCES Bm for attn2 (h0 dead by now)
  attn1_kernel<<<dim3(128, 2), dim3(1024), 0, stream>>>(Mm, adj, s0, n0, Th0, Tl0,
                                                        pO1, pL1, Bm);
  // ---- layer 2 (combine1+gemm2+sn2+split2 fused) ----
  plsum_kernel<<<dim3(32), dim3(256), 0, stream>>>(pL1, il1);
  gemm2_fused_kernel<<<dim3(128), dim3(256), 0, stream>>>(pO1, il1, W1, as1, an1,
                                                          Th1, Tl1, s1, n1);
  attn2_kernel<<<dim3(128, 2), dim3(1024), 0, stream>>>(Mm, Bm, s1, n1, Th1, Tl1, pO2, pL2);
  combine_kernel<64><<<dim3(512), dim3(256), 0, stream>>>(pO2, pL2, out);
}

// Round 18
// 322.502 us; speedup vs baseline: 1.1251x; 1.1251x over previous
//
#include <hip/hip_runtime.h>
#include <hip/hip_bf16.h>

constexpr int NN = 8192;
using uint = unsigned int;

typedef __bf16 bf16x8 __attribute__((ext_vector_type(8)));
typedef float f32x4 __attribute__((ext_vector_type(4)));
typedef float f32x16 __attribute__((ext_vector_type(16)));
typedef unsigned short ushort8_t __attribute__((ext_vector_type(8)));

__device__ __forceinline__ float eluf(float z) { return z > 0.f ? z : __expf(z) - 1.f; }

__device__ __forceinline__ unsigned short bf16_hi(float v) {
  unsigned u = __float_as_uint(v);
  unsigned r = u + 0x7fffu + ((u >> 16) & 1u);
  return (unsigned short)(r >> 16);
}
__device__ __forceinline__ float bf16_tof(unsigned short u) {
  return __uint_as_float(((unsigned)u) << 16);
}

__device__ __forceinline__ uint cvt_pk_bf16(float a, float b) {
  uint r;
  asm("v_cvt_pk_bf16_f32 %0, %1, %2" : "=v"(r) : "v"(a), "v"(b));
  return r;
}

// LDS-only barrier: order LDS ops across the barrier WITHOUT draining vmcnt.
__device__ __forceinline__ void lds_barrier() {
  asm volatile("s_waitcnt lgkmcnt(0)" ::: "memory");
  __builtin_amdgcn_s_barrier();
}

// ---------------------------------------------------------------------------
// prep: grid-partitioned fusion of splitx (512 blocks) + splitw (64 blocks)
// + mask (65536 blocks). Disjoint outputs, read-only inputs -> safe merge.
// ---------------------------------------------------------------------------
__global__ __launch_bounds__(256) void prep_kernel(
    const float* __restrict__ X, const float* __restrict__ W,
    const int* __restrict__ adj, unsigned short* __restrict__ Txh,
    unsigned short* __restrict__ Txl, unsigned short* __restrict__ Twh,
    unsigned short* __restrict__ Twl, uint* __restrict__ Bm) {
  const int bid = blockIdx.x;
  if (bid < 512) {
    // ---- splitx: x [8192][512] -> hi/lo bf16 A-staging layout ----
    const size_t tid = (size_t)bid * 256 + threadIdx.x;
    const int kt = (int)(tid >> 13);
    const int row = (int)(tid & 8191);
    const float* src = X + (size_t)row * 512 + kt * 32;
    #pragma unroll
    for (int kc = 0; kc < 4; ++kc) {
      ushort8_t hi, lo;
      #pragma unroll
      for (int e = 0; e < 8; ++e) {
        const float v = src[kc * 8 + e];
        const unsigned short h = bf16_hi(v);
        hi[e] = h;
        lo[e] = bf16_hi(v - bf16_tof(h));
      }
      const size_t o = ((size_t)(kt * 4 + kc) * 8192 + row) * 8;
      *reinterpret_cast<ushort8_t*>(&Txh[o]) = hi;
      *reinterpret_cast<ushort8_t*>(&Txl[o]) = lo;
    }
  } else if (bid < 576) {
    // ---- splitw: W0 [512][256] -> hi/lo bf16 B-staging layout ----
    const int tid = (bid - 512) * 256 + threadIdx.x;
    const int kb = tid >> 8;
    const int col = tid & 255;
    ushort8_t hi, lo;
    #pragma unroll
    for (int e = 0; e < 8; ++e) {
      const float v = W[(size_t)(kb * 8 + e) * 256 + col];
      const unsigned short h = bf16_hi(v);
      hi[e] = h;
      lo[e] = bf16_hi(v - bf16_tof(h));
    }
    const size_t o = ((size_t)kb * 256 + col) * 8;
    *reinterpret_cast<ushort8_t*>(&Twh[o]) = hi;
    *reinterpret_cast<ushort8_t*>(&Twl[o]) = lo;
  } else {
    // ---- mask: adj (int32 0/1) -> bitmask ----
    const size_t tg = (size_t)(bid - 576) * 256 + threadIdx.x;
    const int4 a = *reinterpret_cast<const int4*>(&adj[tg * 4]);
    uint nib = (a.x > 0 ? 1u : 0u) | (a.y > 0 ? 2u : 0u) |
               (a.z > 0 ? 4u : 0u) | (a.w > 0 ? 8u : 0u);
    const int lane = threadIdx.x & 63;
    uint v = nib << ((lane & 7) * 4);
    v |= __shfl_xor(v, 1);
    v |= __shfl_xor(v, 2);
    v |= __shfl_xor(v, 4);
    if ((lane & 7) == 0) Bm[tg >> 3] = v;
  }
}

// ---------------------------------------------------------------------------
// gemm1_mfma: h0 = x @ W0 via bf16x3 MFMA (32x32x16), 256 blocks x 512 thr.
// Epilogue FUSES split1: writes h0 (for sn1) AND Th0/Tl0 in split layout.
// ---------------------------------------------------------------------------
__global__ __launch_bounds__(512) void gemm1_mfma_kernel(
    const unsigned short* __restrict__ Axh, const unsigned short* __restrict__ Axl,
    const unsigned short* __restrict__ Bwh, const unsigned short* __restrict__ Bwl,
    float* __restrict__ C, unsigned short* __restrict__ Th,
    unsigned short* __restrict__ Tl) {
  const int t = threadIdx.x;
  const int lane = t & 63;
  const int cf = t >> 6;
  const int i0 = blockIdx.x * 32;
  const int col = cf * 32 + (lane & 31);
  const size_t abase = ((size_t)(lane >> 5) * 8192 + i0 + (lane & 31)) * 8;
  const size_t bbase = ((size_t)(lane >> 5) * 256 + col) * 8;

  f32x16 acc;
  #pragma unroll
  for (int i = 0; i < 16; ++i) acc[i] = 0.f;

  #pragma unroll 2
  for (int kt = 0; kt < 16; ++kt) {
    const size_t at = (size_t)kt * 4 * 8192 * 8;
    const size_t bt = (size_t)kt * 4 * 256 * 8;
    #pragma unroll
    for (int h = 0; h < 2; ++h) {
      const size_t ao = at + (size_t)h * 2 * 8192 * 8 + abase;
      const size_t bo = bt + (size_t)h * 2 * 256 * 8 + bbase;
      const bf16x8 ah = *reinterpret_cast<const bf16x8*>(Axh + ao);
      const bf16x8 al = *reinterpret_cast<const bf16x8*>(Axl + ao);
      const bf16x8 bh = *reinterpret_cast<const bf16x8*>(Bwh + bo);
      const bf16x8 bl = *reinterpret_cast<const bf16x8*>(Bwl + bo);
      acc = __builtin_amdgcn_mfma_f32_32x32x16_bf16(al, bh, acc, 0, 0, 0);
      acc = __builtin_amdgcn_mfma_f32_32x32x16_bf16(ah, bl, acc, 0, 0, 0);
      acc = __builtin_amdgcn_mfma_f32_32x32x16_bf16(ah, bh, acc, 0, 0, 0);
    }
  }

  #pragma unroll
  for (int reg = 0; reg < 16; ++reg) {
    const int row = (reg & 3) + 8 * (reg >> 2) + 4 * (lane >> 5);
    const float v = acc[reg];
    C[(size_t)(i0 + row) * 256 + col] = v;
    const unsigned short h = bf16_hi(v);
    const unsigned short l = bf16_hi(v - bf16_tof(h));
    const size_t o = ((size_t)(blockIdx.x * 4 + (row >> 3)) * 256 + col) * 8 + (row & 7);
    Th[o] = h;
    Tl[o] = l;
  }
}

// ---------------------------------------------------------------------------
// s[i] = h[i].a_self ; n[i] = h[i].a_neigh   (one wave per row) — layer 1
// ---------------------------------------------------------------------------
template<int FOUT>
__global__ __launch_bounds__(256) void sn_kernel(
    const float* __restrict__ H, const float* __restrict__ a_self,
    const float* __restrict__ a_neigh, float* __restrict__ s, float* __restrict__ n) {
  const int wave = threadIdx.x >> 6;
  const int lane = threadIdx.x & 63;
  const int row = blockIdx.x * 4 + wave;
  float ds = 0.f, dn = 0.f;
  #pragma unroll
  for (int c = lane; c < FOUT; c += 64) {
    const float h = H[(size_t)row * FOUT + c];
    ds += h * a_self[c];
    dn += h * a_neigh[c];
  }
  #pragma unroll
  for (int off = 32; off > 0; off >>= 1) {
    ds += __shfl_down(ds, off);
    dn += __shfl_down(dn, off);
  }
  if (lane == 0) { s[row] = ds; n[row] = dn; }
}

// ---------------------------------------------------------------------------
// combine2: out = elu((pO[0]+pO[1]) / (pL[0]+pL[1]))   (final output)
// ---------------------------------------------------------------------------
template<int F>
__global__ __launch_bounds__(256) void combine_kernel(
    const float* __restrict__ pO, const float* __restrict__ pL, float* __restrict__ out) {
  const size_t q = (size_t)blockIdx.x * 256 + threadIdx.x;
  const size_t base = q * 4;
  const int row = (int)(base / F);
  const float4 a = *reinterpret_cast<const float4*>(pO + base);
  const float4 b = *reinterpret_cast<const float4*>(pO + (size_t)8192 * F + base);
  const float il = 1.0f / (pL[row] + pL[8192 + row]);
  float4 o;
  o.x = eluf((a.x + b.x) * il);
  o.y = eluf((a.y + b.y) * il);
  o.z = eluf((a.z + b.z) * il);
  o.w = eluf((a.w + b.w) * il);
  *reinterpret_cast<float4*>(out + base) = o;
}

// ---------------------------------------------------------------------------
// gemm2_fused: h1 = elu((pO1_0+pO1_1)*il) @ W1 with il computed inline from
// pL1; epilogue fuses sn2 + split2 (x1 and h1 never materialized).
// ---------------------------------------------------------------------------
__global__ __launch_bounds__(256) void gemm2_fused_kernel(
    const float* __restrict__ pO1, const float* __restrict__ pL1,
    const float* __restrict__ W, const float* __restrict__ a_self,
    const float* __restrict__ a_neigh, unsigned short* __restrict__ Th,
    unsigned short* __restrict__ Tl, float* __restrict__ s1,
    float* __restrict__ n1) {
  constexpr int K = 256, NOUT = 64, BM = 64, BK = 16;
  const size_t seg = (size_t)8192 * 256;
  __shared__ __align__(16) float As[BK][BM + 4];
  __shared__ __align__(16) float Ws[BK][NOUT];
  __shared__ float red_s[64][17];
  __shared__ float red_n[64][17];
  const int t = threadIdx.x;
  const int i0 = blockIdx.x * BM;
  const int tr = t >> 4;
  const int tc = t & 15;
  const int lr = t >> 2;
  const int lk = (t & 3) * 4;
  const int wk = t >> 4;
  const int wc = (t & 15) * 4;
  const float ilr = 1.0f / (pL1[i0 + lr] + pL1[8192 + i0 + lr]);
  float acc[4][4] = {};
  for (int k0 = 0; k0 < K; k0 += BK) {
    const size_t aoff = (size_t)(i0 + lr) * 256 + k0 + lk;
    const float4 p0 = *reinterpret_cast<const float4*>(&pO1[aoff]);
    const float4 p1 = *reinterpret_cast<const float4*>(&pO1[seg + aoff]);
    As[lk + 0][lr] = eluf((p0.x + p1.x) * ilr);
    As[lk + 1][lr] = eluf((p0.y + p1.y) * ilr);
    As[lk + 2][lr] = eluf((p0.z + p1.z) * ilr);
    As[lk + 3][lr] = eluf((p0.w + p1.w) * ilr);
    *reinterpret_cast<float4*>(&Ws[wk][wc]) =
        *reinterpret_cast<const float4*>(&W[(size_t)(k0 + wk) * NOUT + wc]);
    __syncthreads();
    #pragma unroll
    for (int kk = 0; kk < BK; ++kk) {
      const float4 av = *reinterpret_cast<const float4*>(&As[kk][4 * tr]);
      const float4 wv = *reinterpret_cast<const float4*>(&Ws[kk][4 * tc]);
      const float a[4] = {av.x, av.y, av.z, av.w};
      const float w[4] = {wv.x, wv.y, wv.z, wv.w};
      #pragma unroll
      for (int i = 0; i < 4; ++i)
        #pragma unroll
        for (int j = 0; j < 4; ++j) acc[i][j] += a[i] * w[j];
    }
    __syncthreads();
  }
  float asv[4], anv[4];
  #pragma unroll
  for (int j = 0; j < 4; ++j) {
    asv[j] = a_self[4 * tc + j];
    anv[j] = a_neigh[4 * tc + j];
  }
  #pragma unroll
  for (int i = 0; i < 4; ++i) {
    float ps = 0.f, pn = 0.f;
    #pragma unroll
    for (int j = 0; j < 4; ++j) { ps += acc[i][j] * asv[j]; pn += acc[i][j] * anv[j]; }
    red_s[4 * tr + i][tc] = ps;
    red_n[4 * tr + i][tc] = pn;
  }
  #pragma unroll
  for (int i = 0; i < 4; ++i) {
    const int row = 4 * tr + i;
    const int tile = 2 * blockIdx.x + (row >> 5);
    const int kc = (row >> 3) & 3;
    const int e = row & 7;
    #pragma unroll
    for (int j = 0; j < 4; ++j) {
      const int col = 4 * tc + j;
      const float v = acc[i][j];
      const unsigned short h = bf16_hi(v);
      const unsigned short l = bf16_hi(v - bf16_tof(h));
      const size_t o = ((size_t)(tile * 4 + kc) * 64 + col) * 8 + e;
      Th[o] = h;
      Tl[o] = l;
    }
  }
  __syncthreads();
  if (t < 64) {
    float ss = 0.f, nn = 0.f;
    #pragma unroll
    for (int q = 0; q < 16; ++q) { ss += red_s[t][q]; nn += red_n[t][q]; }
    s1[i0 + t] = ss;
    n1[i0 + t] = nn;
  }
}

// ---------------------------------------------------------------------------
// Layer-1 fused attention. Grid (128,2): block = 64 rows (2 rowgroups) x j-half.
// (R16-proven form: consumes precomputed bitmask Bm.)
// ---------------------------------------------------------------------------
__global__ __launch_bounds__(1024, 4) void attn1_kernel(
    const float* __restrict__ Mm, const uint* __restrict__ Bm,
    const float* __restrict__ sv, const float* __restrict__ nv,
    const unsigned short* __restrict__ Th, const unsigned short* __restrict__ Tl,
    float* __restrict__ pO, float* __restrict__ pL) {
  constexpr int F = 256, NT = 4096 / 64;
  __shared__ __align__(16) uint Pa[2][2][2][8 * 132];  // [buf][part][rg][g*132+r*4+q]
  __shared__ __align__(16) float nvs[8192];            // [0..4095]=nv half; full=scratch
  __shared__ float l_lds[64];

  const int t = threadIdx.x;
  const int lane = t & 63;
  const int w = t >> 6;
  const int cf = w & 7;
  const int ks = w >> 3;
  const int r = t >> 5;              // score row 0..31 (per rowgroup)
  const int p2 = t & 31;             // col pair 2p2,2p2+1 (of 64)
  const int i0 = blockIdx.x * 64;
  const int jh = blockIdx.y;
  const size_t jbase = (size_t)jh * 4096;
  const int jt = jh * 128;           // tile32 base

  reinterpret_cast<float4*>(nvs)[t] = reinterpret_cast<const float4*>(nv + jbase)[t];

  const float svrA = sv[i0 + r];
  const float svrB = sv[i0 + 32 + r];
  const size_t mrowA = (size_t)(i0 + r) * NN + jbase;
  const size_t mrowB = mrowA + (size_t)32 * NN;
  const uint* mkrowA = Bm + (size_t)(i0 + r) * (NN / 32) + jh * 128;
  const uint* mkrowB = mkrowA + (size_t)32 * (NN / 32);
  const int col = cf * 32 + (lane & 31);
  const size_t bo0 = ((size_t)(lane >> 5) * F + col) * 8;
  const int pidx = (p2 >> 2) * 132 + r * 4 + (p2 & 3);
  const int aidx = (ks * 4 + (lane >> 5)) * 132 + (lane & 31) * 4;

  float2 MA_e = *reinterpret_cast<const float2*>(&Mm[mrowA + 2 * p2]);
  float2 MA_o = *reinterpret_cast<const float2*>(&Mm[mrowA + 64 + 2 * p2]);
  float2 MB_e = *reinterpret_cast<const float2*>(&Mm[mrowB + 2 * p2]);
  float2 MB_o = *reinterpret_cast<const float2*>(&Mm[mrowB + 64 + 2 * p2]);
  uint mkA_e = mkrowA[p2 >> 4];
  uint mkA_o = mkrowA[2 + (p2 >> 4)];
  uint mkB_e = mkrowB[p2 >> 4];
  uint mkB_o = mkrowB[2 + (p2 >> 4)];
  const size_t tb0 = (size_t)(jt + ks) * 8192;
  bf16x8 bh0_e = *reinterpret_cast<const bf16x8*>(Th + tb0 + bo0);
  bf16x8 bl0_e = *reinterpret_cast<const bf16x8*>(Tl + tb0 + bo0);
  bf16x8 bh1_e = *reinterpret_cast<const bf16x8*>(Th + tb0 + bo0 + 4096);
  bf16x8 bl1_e = *reinterpret_cast<const bf16x8*>(Tl + tb0 + bo0 + 4096);
  bf16x8 bh0_o, bl0_o, bh1_o, bl1_o;

  float rsumA = 0.f, rsumB = 0.f;
  f32x16 accA, accB;
  #pragma unroll
  for (int i = 0; i < 16; ++i) { accA[i] = 0.f; accB[i] = 0.f; }

  __syncthreads();   // nvs staged

  float2 nv_e = *reinterpret_cast<const float2*>(&nvs[2 * p2]);
  float2 nv_o = *reinterpret_cast<const float2*>(&nvs[64 + 2 * p2]);

#define STEP1(TJ, MCA, MKA, MCB, MKB, NVC, BH0C, BL0C, BH1C, BL1C, BH0N, BL0N, BH1N, BL1N) \
  {                                                                               \
    const int t_j = (TJ);                                                         \
    const int jb = (t_j + 1 < NT) ? t_j + 1 : 0;                                  \
    const size_t tb = (size_t)(jt + 2 * jb + ks) * 8192;                          \
    BH0N = *reinterpret_cast<const bf16x8*>(Th + tb + bo0);                       \
    BL0N = *reinterpret_cast<const bf16x8*>(Tl + tb + bo0);                       \
    BH1N = *reinterpret_cast<const bf16x8*>(Th + tb + bo0 + 4096);                \
    BL1N = *reinterpret_cast<const bf16x8*>(Tl + tb + bo0 + 4096);                \
    float e0 = (svrA + NVC.x) * MCA.x; e0 = fmaxf(e0, 0.2f * e0); e0 = fminf(e0, 70.f); \
    float e1 = (svrA + NVC.y) * MCA.y; e1 = fmaxf(e1, 0.2f * e1); e1 = fminf(e1, 70.f); \
    float e2 = (svrB + NVC.x) * MCB.x; e2 = fmaxf(e2, 0.2f * e2); e2 = fminf(e2, 70.f); \
    float e3 = (svrB + NVC.y) * MCB.y; e3 = fmaxf(e3, 0.2f * e3); e3 = fminf(e3, 70.f); \
    const float pA0 = ((MKA >> (2 * (p2 & 15))) & 1u) ? __expf(e0) : 0.f;         \
    const float pA1 = ((MKA >> (2 * (p2 & 15) + 1)) & 1u) ? __expf(e1) : 0.f;     \
    const float pB0 = ((MKB >> (2 * (p2 & 15))) & 1u) ? __expf(e2) : 0.f;         \
    const float pB1 = ((MKB >> (2 * (p2 & 15) + 1)) & 1u) ? __expf(e3) : 0.f;     \
    rsumA += pA0 + pA1; rsumB += pB0 + pB1;                                       \
    const int jm = (t_j + 2 < NT) ? t_j + 2 : 0;                                  \
    MCA = *reinterpret_cast<const float2*>(&Mm[mrowA + (size_t)jm * 64 + 2 * p2]); \
    MKA = mkrowA[jm * 2 + (p2 >> 4)];                                             \
    MCB = *reinterpret_cast<const float2*>(&Mm[mrowB + (size_t)jm * 64 + 2 * p2]); \
    MKB = mkrowB[jm * 2 + (p2 >> 4)];                                             \
    NVC = *reinterpret_cast<const float2*>(&nvs[jm * 64 + 2 * p2]);               \
    const uint hwA = cvt_pk_bf16(pA0, pA1);                                       \
    const uint lwA = cvt_pk_bf16(pA0 - __uint_as_float(hwA << 16),                \
                                 pA1 - __uint_as_float(hwA & 0xffff0000u));       \
    const uint hwB = cvt_pk_bf16(pB0, pB1);                                       \
    const uint lwB = cvt_pk_bf16(pB0 - __uint_as_float(hwB << 16),                \
                                 pB1 - __uint_as_float(hwB & 0xffff0000u));       \
    Pa[t_j & 1][0][0][pidx] = hwA;                                                \
    Pa[t_j & 1][1][0][pidx] = lwA;                                                \
    Pa[t_j & 1][0][1][pidx] = hwB;                                                \
    Pa[t_j & 1][1][1][pidx] = lwB;                                                \
    lds_barrier();                                                                \
    const bf16x8 ahA0 = *reinterpret_cast<const bf16x8*>(&Pa[t_j & 1][0][0][aidx]);       \
    const bf16x8 alA0 = *reinterpret_cast<const bf16x8*>(&Pa[t_j & 1][1][0][aidx]);       \
    const bf16x8 ahA1 = *reinterpret_cast<const bf16x8*>(&Pa[t_j & 1][0][0][aidx + 264]); \
    const bf16x8 alA1 = *reinterpret_cast<const bf16x8*>(&Pa[t_j & 1][1][0][aidx + 264]); \
    const bf16x8 ahB0 = *reinterpret_cast<const bf16x8*>(&Pa[t_j & 1][0][1][aidx]);       \
    const bf16x8 alB0 = *reinterpret_cast<const bf16x8*>(&Pa[t_j & 1][1][1][aidx]);       \
    const bf16x8 ahB1 = *reinterpret_cast<const bf16x8*>(&Pa[t_j & 1][0][1][aidx + 264]); \
    const bf16x8 alB1 = *reinterpret_cast<const bf16x8*>(&Pa[t_j & 1][1][1][aidx + 264]); \
    accA = __builtin_amdgcn_mfma_f32_32x32x16_bf16(alA0, BH0C, accA, 0, 0, 0);    \
    accB = __builtin_amdgcn_mfma_f32_32x32x16_bf16(alB0, BH0C, accB, 0, 0, 0);    \
    accA = __builtin_amdgcn_mfma_f32_32x32x16_bf16(ahA0, BL0C, accA, 0, 0, 0);    \
    accB = __builtin_amdgcn_mfma_f32_32x32x16_bf16(ahB0, BL0C, accB, 0, 0, 0);    \
    accA = __builtin_amdgcn_mfma_f32_32x32x16_bf16(ahA0, BH0C, accA, 0, 0, 0);    \
    accB = __builtin_amdgcn_mfma_f32_32x32x16_bf16(ahB0, BH0C, accB, 0, 0, 0);    \
    accA = __builtin_amdgcn_mfma_f32_32x32x16_bf16(alA1, BH1C, accA, 0, 0, 0);    \
    accB = __builtin_amdgcn_mfma_f32_32x32x16_bf16(alB1, BH1C, accB, 0, 0, 0);    \
    accA = __builtin_amdgcn_mfma_f32_32x32x16_bf16(ahA1, BL1C, accA, 0, 0, 0);    \
    accB = __builtin_amdgcn_mfma_f32_32x32x16_bf16(ahB1, BL1C, accB, 0, 0, 0);    \
    accA = __builtin_amdgcn_mfma_f32_32x32x16_bf16(ahA1, BH1C, accA, 0, 0, 0);    \
    accB = __builtin_amdgcn_mfma_f32_32x32x16_bf16(ahB1, BH1C, accB, 0, 0, 0);    \
  }

  for (int tj = 0; tj < NT; tj += 2) {
    STEP1(tj,     MA_e, mkA_e, MB_e, mkB_e, nv_e, bh0_e, bl0_e, bh1_e, bl1_e, bh0_o, bl0_o, bh1_o, bl1_o)
    STEP1(tj + 1, MA_o, mkA_o, MB_o, mkB_o, nv_o, bh0_o, bl0_o, bh1_o, bl1_o, bh0_e, bl0_e, bh1_e, bl1_e)
  }
#undef STEP1

  #pragma unroll
  for (int off = 1; off < 32; off <<= 1) {
    rsumA += __shfl_xor(rsumA, off);
    rsumB += __shfl_xor(rsumB, off);
  }
  if (p2 == 0) { l_lds[r] = rsumA; l_lds[32 + r] = rsumB; }
  __syncthreads();
  if (t < 64) pL[(size_t)jh * 8192 + i0 + t] = l_lds[t];

  // k-half reduce via LDS scratch (reuse nvs, 32KB), rowgroup A then B.
  float* scratch = nvs;
  if (ks == 1) {
    #pragma unroll
    for (int reg = 0; reg < 16; ++reg) scratch[cf * 1024 + reg * 64 + lane] = accA[reg];
  }
  __syncthreads();
  if (ks == 0) {
    #pragma unroll
    for (int reg = 0; reg < 16; ++reg) {
      const int row = (reg & 3) + 8 * (reg >> 2) + 4 * (lane >> 5);
      pO[(size_t)jh * 8192 * F + (size_t)(i0 + row) * F + col] =
          accA[reg] + scratch[cf * 1024 + reg * 64 + lane];
    }
  }
  __syncthreads();
  if (ks == 1) {
    #pragma unroll
    for (int reg = 0; reg < 16; ++reg) scratch[cf * 1024 + reg * 64 + lane] = accB[reg];
  }
  __syncthreads();
  if (ks == 0) {
    #pragma unroll
    for (int reg = 0; reg < 16; ++reg) {
      const int row = (reg & 3) + 8 * (reg >> 2) + 4 * (lane >> 5);
      pO[(size_t)jh * 8192 * F + (size_t)(i0 + 32 + row) * F + col] =
          accB[reg] + scratch[cf * 1024 + reg * 64 + lane];
    }
  }
}

// ---------------------------------------------------------------------------
// Layer-2 fused attention. Grid (128,2): 64 rows x j-half, 1024 thr.
// ---------------------------------------------------------------------------
__global__ __launch_bounds__(1024, 4) void attn2_kernel(
    const float* __restrict__ Mm, const uint* __restrict__ Bm,
    const float* __restrict__ sv, const float* __restrict__ nv,
    const unsigned short* __restrict__ Th, const unsigned short* __restrict__ Tl,
    float* __restrict__ pO, float* __restrict__ pL) {
  constexpr int F = 64, NT = 4096 / 64;
  __shared__ __align__(16) uint Pa[2][2][2][8 * 132];
  __shared__ __align__(16) float nvs[4096];
  __shared__ float l_lds[64];

  const int t = threadIdx.x;
  const int lane = t & 63;
  const int w = t >> 6;
  const int rb = w & 1;
  const int cf = (w >> 1) & 3;
  const int ks = w >> 3;
  const int r = t >> 5;
  const int p2 = t & 31;
  const int i0 = blockIdx.x * 64;
  const int jh = blockIdx.y;
  const size_t jbase = (size_t)jh * 4096;
  const int jt = jh * 128;

  reinterpret_cast<float4*>(nvs)[t] = reinterpret_cast<const float4*>(nv + jbase)[t];

  const float svrA = sv[i0 + r];
  const float svrB = sv[i0 + 32 + r];
  const size_t mrowA = (size_t)(i0 + r) * NN + jbase;
  const size_t mrowB = mrowA + (size_t)32 * NN;
  const uint* mkrowA = Bm + (size_t)(i0 + r) * (NN / 32) + jh * 128;
  const uint* mkrowB = mkrowA + (size_t)32 * (NN / 32);
  const int col = cf * 16 + (lane & 15);
  const size_t bo2 = ((size_t)(lane >> 4) * F + col) * 8;
  const int pidx = (p2 >> 2) * 132 + r * 4 + (p2 & 3);
  const int aidx = (ks * 4 + (lane >> 4)) * 132 + (rb * 16 + (lane & 15)) * 4;

  float2 MA_e = *reinterpret_cast<const float2*>(&Mm[mrowA + 2 * p2]);
  float2 MA_o = *reinterpret_cast<const float2*>(&Mm[mrowA + 64 + 2 * p2]);
  float2 MB_e = *reinterpret_cast<const float2*>(&Mm[mrowB + 2 * p2]);
  float2 MB_o = *reinterpret_cast<const float2*>(&Mm[mrowB + 64 + 2 * p2]);
  uint mkA_e = mkrowA[p2 >> 4];
  uint mkA_o = mkrowA[2 + (p2 >> 4)];
  uint mkB_e = mkrowB[p2 >> 4];
  uint mkB_o = mkrowB[2 + (p2 >> 4)];
  const size_t tb0 = (size_t)(jt + ks) * 2048;
  bf16x8 bh_e = *reinterpret_cast<const bf16x8*>(Th + tb0 + bo2);
  bf16x8 bl_e = *reinterpret_cast<const bf16x8*>(Tl + tb0 + bo2);
  bf16x8 bh_o, bl_o;

  float rsumA = 0.f, rsumB = 0.f;
  f32x4 accA = {0.f, 0.f, 0.f, 0.f}, accA2 = {0.f, 0.f, 0.f, 0.f};
  f32x4 accB = {0.f, 0.f, 0.f, 0.f}, accB2 = {0.f, 0.f, 0.f, 0.f};

  __syncthreads();   // nvs staged

  float2 nv_e = *reinterpret_cast<const float2*>(&nvs[2 * p2]);
  float2 nv_o = *reinterpret_cast<const float2*>(&nvs[64 + 2 * p2]);

#define STEP2(TJ, MCA, MKA, MCB, MKB, NVC, BHC, BLC, BHN, BLN)                    \
  {                                                                               \
    const int t_j = (TJ);                                                         \
    const int jb = (t_j + 1 < NT) ? t_j + 1 : 0;                                  \
    const size_t tb = (size_t)(jt + 2 * jb + ks) * 2048;                          \
    BHN = *reinterpret_cast<const bf16x8*>(Th + tb + bo2);                        \
    BLN = *reinterpret_cast<const bf16x8*>(Tl + tb + bo2);                        \
    float e0 = (svrA + NVC.x) * MCA.x; e0 = fmaxf(e0, 0.2f * e0); e0 = fminf(e0, 70.f); \
    float e1 = (svrA + NVC.y) * MCA.y; e1 = fmaxf(e1, 0.2f * e1); e1 = fminf(e1, 70.f); \
    float e2 = (svrB + NVC.x) * MCB.x; e2 = fmaxf(e2, 0.2f * e2); e2 = fminf(e2, 70.f); \
    float e3 = (svrB + NVC.y) * MCB.y; e3 = fmaxf(e3, 0.2f * e3); e3 = fminf(e3, 70.f); \
    const float pA0 = ((MKA >> (2 * (p2 & 15))) & 1u) ? __expf(e0) : 0.f;         \
    const float pA1 = ((MKA >> (2 * (p2 & 15) + 1)) & 1u) ? __expf(e1) : 0.f;     \
    const float pB0 = ((MKB >> (2 * (p2 & 15))) & 1u) ? __expf(e2) : 0.f;         \
    const float pB1 = ((MKB >> (2 * (p2 & 15) + 1)) & 1u) ? __expf(e3) : 0.f;     \
    rsumA += pA0 + pA1; rsumB += pB0 + pB1;                                       \
    const int jm = (t_j + 2 < NT) ? t_j + 2 : 0;                                  \
    MCA = *reinterpret_cast<const float2*>(&Mm[mrowA + (size_t)jm * 64 + 2 * p2]); \
    MKA = mkrowA[jm * 2 + (p2 >> 4)];                                             \
    MCB = *reinterpret_cast<const float2*>(&Mm[mrowB + (size_t)jm * 64 + 2 * p2]); \
    MKB = mkrowB[jm * 2 + (p2 >> 4)];                                             \
    NVC = *reinterpret_cast<const float2*>(&nvs[jm * 64 + 2 * p2]);               \
    const uint hwA = cvt_pk_bf16(pA0, pA1);                                       \
    const uint lwA = cvt_pk_bf16(pA0 - __uint_as_float(hwA << 16),                \
                                 pA1 - __uint_as_float(hwA & 0xffff0000u));       \
    const uint hwB = cvt_pk_bf16(pB0, pB1);                                       \
    const uint lwB = cvt_pk_bf16(pB0 - __uint_as_float(hwB << 16),                \
                                 pB1 - __uint_as_float(hwB & 0xffff0000u));       \
    Pa[t_j & 1][0][0][pidx] = hwA;                                                \
    Pa[t_j & 1][1][0][pidx] = lwA;                                                \
    Pa[t_j & 1][0][1][pidx] = hwB;                                                \
    Pa[t_j & 1][1][1][pidx] = lwB;                                                \
    lds_barrier();                                                                \
    const bf16x8 ahA = *reinterpret_cast<const bf16x8*>(&Pa[t_j & 1][0][0][aidx]); \
    const bf16x8 alA = *reinterpret_cast<const bf16x8*>(&Pa[t_j & 1][1][0][aidx]); \
    const bf16x8 ahB = *reinterpret_cast<const bf16x8*>(&Pa[t_j & 1][0][1][aidx]); \
    const bf16x8 alB = *reinterpret_cast<const bf16x8*>(&Pa[t_j & 1][1][1][aidx]); \
    accA  = __builtin_amdgcn_mfma_f32_16x16x32_bf16(alA, BHC, accA, 0, 0, 0);     \
    accB  = __builtin_amdgcn_mfma_f32_16x16x32_bf16(alB, BHC, accB, 0, 0, 0);     \
    accA2 = __builtin_amdgcn_mfma_f32_16x16x32_bf16(ahA, BLC, accA2, 0, 0, 0);    \
    accB2 = __builtin_amdgcn_mfma_f32_16x16x32_bf16(ahB, BLC, accB2, 0, 0, 0);    \
    accA  = __builtin_amdgcn_mfma_f32_16x16x32_bf16(ahA, BHC, accA, 0, 0, 0);     \
    accB  = __builtin_amdgcn_mfma_f32_16x16x32_bf16(ahB, BHC, accB, 0, 0, 0);     \
  }

  for (int tj = 0; tj < NT; tj += 2) {
    STEP2(tj,     MA_e, mkA_e, MB_e, mkB_e, nv_e, bh_e, bl_e, bh_o, bl_o)
    STEP2(tj + 1, MA_o, mkA_o, MB_o, mkB_o, nv_o, bh_o, bl_o, bh_e, bl_e)
  }
#undef STEP2

  #pragma unroll
  for (int off = 1; off < 32; off <<= 1) {
    rsumA += __shfl_xor(rsumA, off);
    rsumB += __shfl_xor(rsumB, off);
  }
  if (p2 == 0) { l_lds[r] = rsumA; l_lds[32 + r] = rsumB; }
  __syncthreads();
  if (t < 64) pL[(size_t)jh * 8192 + i0 + t] = l_lds[t];

  float* scratch = nvs;
  if (ks == 1) {
    #pragma unroll
    for (int reg = 0; reg < 4; ++reg)
      scratch[(w & 7) * 256 + reg * 64 + lane] = accA[reg] + accA2[reg];
  }
  __syncthreads();
  if (ks == 0) {
    #pragma unroll
    for (int reg = 0; reg < 4; ++reg) {
      const int row = rb * 16 + (lane >> 4) * 4 + reg;
      pO[(size_t)jh * 8192 * F + (size_t)(i0 + row) * F + col] =
          accA[reg] + accA2[reg] + scratch[(w & 7) * 256 + reg * 64 + lane];
    }
  }
  __syncthreads();
  if (ks == 1) {
    #pragma unroll
    for (int reg = 0; reg < 4; ++reg)
      scratch[(w & 7) * 256 + reg * 64 + lane] = accB[reg] + accB2[reg];
  }
  __syncthreads();
  if (ks == 0) {
    #pragma unroll
    for (int reg = 0; reg < 4; ++reg) {
      const int row = rb * 16 + (lane >> 4) * 4 + reg;
      pO[(size_t)jh * 8192 * F + (size_t)(i0 + 32 + row) * F + col] =
          accB[reg] + accB2[reg] + scratch[(w & 7) * 256 + reg * 64 + lane];
    }
  }
}

// ---------------------------------------------------------------------------
extern "C" void kernel_launch(void* const* d_in, const int* in_sizes, int n_in,
                              void* d_out, int out_size, void* d_ws, size_t ws_size,
                              hipStream_t stream) {
  const float* x   = (const float*)d_in[0];
  const int*   adj = (const int*)  d_in[1];
  const float* Mm  = (const float*)d_in[2];
  const float* W0  = (const float*)d_in[3];
  const float* as0 = (const float*)d_in[4];
  const float* an0 = (const float*)d_in[5];
  const float* W1  = (const float*)d_in[6];
  const float* as1 = (const float*)d_in[7];
  const float* an1 = (const float*)d_in[8];
  float* out = (float*)d_out;

  char* ws = (char*)d_ws;
  const size_t MB = 1048576;
  const size_t KB = 1024;
  float* h0  = (float*)(ws);                              // 8 MB (dead after sn1)
  unsigned short* Th0 = (unsigned short*)(ws + 18 * MB);  // 4 MB
  unsigned short* Tl0 = (unsigned short*)(ws + 22 * MB);  // 4 MB
  unsigned short* Th1 = (unsigned short*)(ws + 26 * MB);  // 1 MB
  unsigned short* Tl1 = (unsigned short*)(ws + 27 * MB);  // 1 MB
  float* s0  = (float*)(ws + 28 * MB);
  float* n0  = (float*)(ws + 28 * MB + 32 * KB);
  float* s1  = (float*)(ws + 28 * MB + 64 * KB);
  float* n1  = (float*)(ws + 28 * MB + 96 * KB);
  float* pL1 = (float*)(ws + 28 * MB + 128 * KB);         // 64 KB [2][8192]
  float* pL2 = (float*)(ws + 28 * MB + 192 * KB);         // 64 KB
  float* pO1 = (float*)(ws + 29 * MB);                    // 16 MB [2][8192][256]
  float* pO2 = (float*)(ws + 29 * MB);                    // 4 MB  [2][8192][64] (pO1 dead)
  unsigned short* Txh = (unsigned short*)(ws + 64 * MB);  // 8 MB (x split hi)
  unsigned short* Txl = (unsigned short*)(ws + 72 * MB);  // 8 MB (x split lo)
  unsigned short* Twh = (unsigned short*)(ws + 80 * MB);  // 256 KB (W0 split hi)
  unsigned short* Twl = (unsigned short*)(ws + 81 * MB);  // 256 KB (W0 split lo)
  uint*  Bm  = (uint*)(ws + 82 * MB);                     // 8 MB (no aliasing: prep runs first)

  // ---- prep: splitx + splitw + mask in one launch ----
  prep_kernel<<<dim3(66112), dim3(256), 0, stream>>>(x, W0, adj, Txh, Txl, Twh, Twl, Bm);
  // ---- layer 1 ----
  gemm1_mfma_kernel<<<dim3(256), dim3(512), 0, stream>>>(Txh, Txl, Twh, Twl, h0, Th0, Tl0);
  sn_kernel<256><<<dim3(2048), dim3(256), 0, stream>>>(h0, as0, an0, s0, n0);
  attn1_kernel<<<dim3(128, 2), dim3(1024), 0, stream>>>(Mm, Bm, s0, n0, Th0, Tl0, pO1, pL1);
  // ---- layer 2 (combine1+gemm2+sn2+split2 fused; il inline) ----
  gemm2_fused_kernel<<<dim3(128), dim3(256), 0, stream>>>(pO1, pL1, W1, as1, an1,
                                                          Th1, Tl1, s1, n1);
  attn2_kernel<<<dim3(128, 2), dim3(1024), 0, stream>>>(Mm, Bm, s1, n1, Th1, Tl1, pO2, pL2);
  combine_kernel<64><<<dim3(512), dim3(256), 0, stream>>>(pO2, pL2, out);
}

// Round 19
// 318.585 us; speedup vs baseline: 1.1389x; 1.0123x over previous
//
#include <hip/hip_runtime.h>
#include <hip/hip_bf16.h>

constexpr int NN = 8192;
using uint = unsigned int;

typedef __bf16 bf16x8 __attribute__((ext_vector_type(8)));
typedef float f32x4 __attribute__((ext_vector_type(4)));
typedef float f32x16 __attribute__((ext_vector_type(16)));
typedef unsigned short ushort8_t __attribute__((ext_vector_type(8)));

__device__ __forceinline__ float eluf(float z) { return z > 0.f ? z : __expf(z) - 1.f; }

__device__ __forceinline__ unsigned short bf16_hi(float v) {
  unsigned u = __float_as_uint(v);
  unsigned r = u + 0x7fffu + ((u >> 16) & 1u);
  return (unsigned short)(r >> 16);
}
__device__ __forceinline__ float bf16_tof(unsigned short u) {
  return __uint_as_float(((unsigned)u) << 16);
}

__device__ __forceinline__ uint cvt_pk_bf16(float a, float b) {
  uint r;
  asm("v_cvt_pk_bf16_f32 %0, %1, %2" : "=v"(r) : "v"(a), "v"(b));
  return r;
}

// LDS-only barrier: order LDS ops across the barrier WITHOUT draining vmcnt.
__device__ __forceinline__ void lds_barrier() {
  asm volatile("s_waitcnt lgkmcnt(0)" ::: "memory");
  __builtin_amdgcn_s_barrier();
}

// ---------------------------------------------------------------------------
// prep: grid-partitioned fusion of splitx (512 blocks) + splitw (64 blocks)
// + mask (65536 blocks). Disjoint outputs, read-only inputs -> safe merge.
// ---------------------------------------------------------------------------
__global__ __launch_bounds__(256) void prep_kernel(
    const float* __restrict__ X, const float* __restrict__ W,
    const int* __restrict__ adj, unsigned short* __restrict__ Txh,
    unsigned short* __restrict__ Txl, unsigned short* __restrict__ Twh,
    unsigned short* __restrict__ Twl, uint* __restrict__ Bm) {
  const int bid = blockIdx.x;
  if (bid < 512) {
    // ---- splitx: x [8192][512] -> hi/lo bf16 A-staging layout ----
    const size_t tid = (size_t)bid * 256 + threadIdx.x;
    const int kt = (int)(tid >> 13);
    const int row = (int)(tid & 8191);
    const float* src = X + (size_t)row * 512 + kt * 32;
    #pragma unroll
    for (int kc = 0; kc < 4; ++kc) {
      ushort8_t hi, lo;
      #pragma unroll
      for (int e = 0; e < 8; ++e) {
        const float v = src[kc * 8 + e];
        const unsigned short h = bf16_hi(v);
        hi[e] = h;
        lo[e] = bf16_hi(v - bf16_tof(h));
      }
      const size_t o = ((size_t)(kt * 4 + kc) * 8192 + row) * 8;
      *reinterpret_cast<ushort8_t*>(&Txh[o]) = hi;
      *reinterpret_cast<ushort8_t*>(&Txl[o]) = lo;
    }
  } else if (bid < 576) {
    // ---- splitw: W0 [512][256] -> hi/lo bf16 B-staging layout ----
    const int tid = (bid - 512) * 256 + threadIdx.x;
    const int kb = tid >> 8;
    const int col = tid & 255;
    ushort8_t hi, lo;
    #pragma unroll
    for (int e = 0; e < 8; ++e) {
      const float v = W[(size_t)(kb * 8 + e) * 256 + col];
      const unsigned short h = bf16_hi(v);
      hi[e] = h;
      lo[e] = bf16_hi(v - bf16_tof(h));
    }
    const size_t o = ((size_t)kb * 256 + col) * 8;
    *reinterpret_cast<ushort8_t*>(&Twh[o]) = hi;
    *reinterpret_cast<ushort8_t*>(&Twl[o]) = lo;
  } else {
    // ---- mask: adj (int32 0/1) -> bitmask ----
    const size_t tg = (size_t)(bid - 576) * 256 + threadIdx.x;
    const int4 a = *reinterpret_cast<const int4*>(&adj[tg * 4]);
    uint nib = (a.x > 0 ? 1u : 0u) | (a.y > 0 ? 2u : 0u) |
               (a.z > 0 ? 4u : 0u) | (a.w > 0 ? 8u : 0u);
    const int lane = threadIdx.x & 63;
    uint v = nib << ((lane & 7) * 4);
    v |= __shfl_xor(v, 1);
    v |= __shfl_xor(v, 2);
    v |= __shfl_xor(v, 4);
    if ((lane & 7) == 0) Bm[tg >> 3] = v;
  }
}

// ---------------------------------------------------------------------------
// gemm1_mfma: h0 = x @ W0 via bf16x3 MFMA (32x32x16), 256 blocks x 512 thr.
// Epilogue FUSES split1 (Th0/Tl0 in split layout) AND sn1 (s0/n0 via
// 32-lane-half shfl reduce + per-(row,cf) LDS buckets). h0 never materialized.
// ---------------------------------------------------------------------------
__global__ __launch_bounds__(512) void gemm1_mfma_kernel(
    const unsigned short* __restrict__ Axh, const unsigned short* __restrict__ Axl,
    const unsigned short* __restrict__ Bwh, const unsigned short* __restrict__ Bwl,
    const float* __restrict__ a_self, const float* __restrict__ a_neigh,
    unsigned short* __restrict__ Th, unsigned short* __restrict__ Tl,
    float* __restrict__ s0, float* __restrict__ n0) {
  __shared__ float red_s[32][9];
  __shared__ float red_n[32][9];
  const int t = threadIdx.x;
  const int lane = t & 63;
  const int cf = t >> 6;
  const int i0 = blockIdx.x * 32;
  const int col = cf * 32 + (lane & 31);
  const size_t abase = ((size_t)(lane >> 5) * 8192 + i0 + (lane & 31)) * 8;
  const size_t bbase = ((size_t)(lane >> 5) * 256 + col) * 8;

  f32x16 acc;
  #pragma unroll
  for (int i = 0; i < 16; ++i) acc[i] = 0.f;

  #pragma unroll 2
  for (int kt = 0; kt < 16; ++kt) {
    const size_t at = (size_t)kt * 4 * 8192 * 8;
    const size_t bt = (size_t)kt * 4 * 256 * 8;
    #pragma unroll
    for (int h = 0; h < 2; ++h) {
      const size_t ao = at + (size_t)h * 2 * 8192 * 8 + abase;
      const size_t bo = bt + (size_t)h * 2 * 256 * 8 + bbase;
      const bf16x8 ah = *reinterpret_cast<const bf16x8*>(Axh + ao);
      const bf16x8 al = *reinterpret_cast<const bf16x8*>(Axl + ao);
      const bf16x8 bh = *reinterpret_cast<const bf16x8*>(Bwh + bo);
      const bf16x8 bl = *reinterpret_cast<const bf16x8*>(Bwl + bo);
      acc = __builtin_amdgcn_mfma_f32_32x32x16_bf16(al, bh, acc, 0, 0, 0);
      acc = __builtin_amdgcn_mfma_f32_32x32x16_bf16(ah, bl, acc, 0, 0, 0);
      acc = __builtin_amdgcn_mfma_f32_32x32x16_bf16(ah, bh, acc, 0, 0, 0);
    }
  }

  const float asv = a_self[col];
  const float anv = a_neigh[col];
  #pragma unroll
  for (int reg = 0; reg < 16; ++reg) {
    const int row = (reg & 3) + 8 * (reg >> 2) + 4 * (lane >> 5);
    const float v = acc[reg];
    // fused split1: row within tile = kc*8+e
    const unsigned short h = bf16_hi(v);
    const unsigned short l = bf16_hi(v - bf16_tof(h));
    const size_t o = ((size_t)(blockIdx.x * 4 + (row >> 3)) * 256 + col) * 8 + (row & 7);
    Th[o] = h;
    Tl[o] = l;
    // fused sn1: reduce v*as / v*an over the 32 lanes of this half
    float ps = v * asv;
    float pn = v * anv;
    #pragma unroll
    for (int off = 1; off < 32; off <<= 1) {
      ps += __shfl_xor(ps, off);
      pn += __shfl_xor(pn, off);
    }
    if ((lane & 31) == 0) {
      red_s[row][cf] = ps;   // exactly one writer per (row, cf)
      red_n[row][cf] = pn;
    }
  }
  __syncthreads();
  if (t < 32) {
    float ss = 0.f, nn = 0.f;
    #pragma unroll
    for (int q = 0; q < 8; ++q) { ss += red_s[t][q]; nn += red_n[t][q]; }
    s0[i0 + t] = ss;
    n0[i0 + t] = nn;
  }
}

// ---------------------------------------------------------------------------
// combine2: out = elu((pO[0]+pO[1]) / (pL[0]+pL[1]))   (final output)
// ---------------------------------------------------------------------------
template<int F>
__global__ __launch_bounds__(256) void combine_kernel(
    const float* __restrict__ pO, const float* __restrict__ pL, float* __restrict__ out) {
  const size_t q = (size_t)blockIdx.x * 256 + threadIdx.x;
  const size_t base = q * 4;
  const int row = (int)(base / F);
  const float4 a = *reinterpret_cast<const float4*>(pO + base);
  const float4 b = *reinterpret_cast<const float4*>(pO + (size_t)8192 * F + base);
  const float il = 1.0f / (pL[row] + pL[8192 + row]);
  float4 o;
  o.x = eluf((a.x + b.x) * il);
  o.y = eluf((a.y + b.y) * il);
  o.z = eluf((a.z + b.z) * il);
  o.w = eluf((a.w + b.w) * il);
  *reinterpret_cast<float4*>(out + base) = o;
}

// ---------------------------------------------------------------------------
// gemm2_fused: h1 = elu((pO1_0+pO1_1)*il) @ W1 with il computed inline from
// pL1; epilogue fuses sn2 + split2 (x1 and h1 never materialized).
// ---------------------------------------------------------------------------
__global__ __launch_bounds__(256) void gemm2_fused_kernel(
    const float* __restrict__ pO1, const float* __restrict__ pL1,
    const float* __restrict__ W, const float* __restrict__ a_self,
    const float* __restrict__ a_neigh, unsigned short* __restrict__ Th,
    unsigned short* __restrict__ Tl, float* __restrict__ s1,
    float* __restrict__ n1) {
  constexpr int K = 256, NOUT = 64, BM = 64, BK = 16;
  const size_t seg = (size_t)8192 * 256;
  __shared__ __align__(16) float As[BK][BM + 4];
  __shared__ __align__(16) float Ws[BK][NOUT];
  __shared__ float red_s[64][17];
  __shared__ float red_n[64][17];
  const int t = threadIdx.x;
  const int i0 = blockIdx.x * BM;
  const int tr = t >> 4;
  const int tc = t & 15;
  const int lr = t >> 2;
  const int lk = (t & 3) * 4;
  const int wk = t >> 4;
  const int wc = (t & 15) * 4;
  const float ilr = 1.0f / (pL1[i0 + lr] + pL1[8192 + i0 + lr]);
  float acc[4][4] = {};
  for (int k0 = 0; k0 < K; k0 += BK) {
    const size_t aoff = (size_t)(i0 + lr) * 256 + k0 + lk;
    const float4 p0 = *reinterpret_cast<const float4*>(&pO1[aoff]);
    const float4 p1 = *reinterpret_cast<const float4*>(&pO1[seg + aoff]);
    As[lk + 0][lr] = eluf((p0.x + p1.x) * ilr);
    As[lk + 1][lr] = eluf((p0.y + p1.y) * ilr);
    As[lk + 2][lr] = eluf((p0.z + p1.z) * ilr);
    As[lk + 3][lr] = eluf((p0.w + p1.w) * ilr);
    *reinterpret_cast<float4*>(&Ws[wk][wc]) =
        *reinterpret_cast<const float4*>(&W[(size_t)(k0 + wk) * NOUT + wc]);
    __syncthreads();
    #pragma unroll
    for (int kk = 0; kk < BK; ++kk) {
      const float4 av = *reinterpret_cast<const float4*>(&As[kk][4 * tr]);
      const float4 wv = *reinterpret_cast<const float4*>(&Ws[kk][4 * tc]);
      const float a[4] = {av.x, av.y, av.z, av.w};
      const float w[4] = {wv.x, wv.y, wv.z, wv.w};
      #pragma unroll
      for (int i = 0; i < 4; ++i)
        #pragma unroll
        for (int j = 0; j < 4; ++j) acc[i][j] += a[i] * w[j];
    }
    __syncthreads();
  }
  float asv[4], anv[4];
  #pragma unroll
  for (int j = 0; j < 4; ++j) {
    asv[j] = a_self[4 * tc + j];
    anv[j] = a_neigh[4 * tc + j];
  }
  #pragma unroll
  for (int i = 0; i < 4; ++i) {
    float ps = 0.f, pn = 0.f;
    #pragma unroll
    for (int j = 0; j < 4; ++j) { ps += acc[i][j] * asv[j]; pn += acc[i][j] * anv[j]; }
    red_s[4 * tr + i][tc] = ps;
    red_n[4 * tr + i][tc] = pn;
  }
  #pragma unroll
  for (int i = 0; i < 4; ++i) {
    const int row = 4 * tr + i;
    const int tile = 2 * blockIdx.x + (row >> 5);
    const int kc = (row >> 3) & 3;
    const int e = row & 7;
    #pragma unroll
    for (int j = 0; j < 4; ++j) {
      const int col = 4 * tc + j;
      const float v = acc[i][j];
      const unsigned short h = bf16_hi(v);
      const unsigned short l = bf16_hi(v - bf16_tof(h));
      const size_t o = ((size_t)(tile * 4 + kc) * 64 + col) * 8 + e;
      Th[o] = h;
      Tl[o] = l;
    }
  }
  __syncthreads();
  if (t < 64) {
    float ss = 0.f, nn = 0.f;
    #pragma unroll
    for (int q = 0; q < 16; ++q) { ss += red_s[t][q]; nn += red_n[t][q]; }
    s1[i0 + t] = ss;
    n1[i0 + t] = nn;
  }
}

// ---------------------------------------------------------------------------
// Layer-1 fused attention. Grid (128,2): block = 64 rows (2 rowgroups) x j-half.
// ---------------------------------------------------------------------------
__global__ __launch_bounds__(1024, 4) void attn1_kernel(
    const float* __restrict__ Mm, const uint* __restrict__ Bm,
    const float* __restrict__ sv, const float* __restrict__ nv,
    const unsigned short* __restrict__ Th, const unsigned short* __restrict__ Tl,
    float* __restrict__ pO, float* __restrict__ pL) {
  constexpr int F = 256, NT = 4096 / 64;
  __shared__ __align__(16) uint Pa[2][2][2][8 * 132];  // [buf][part][rg][g*132+r*4+q]
  __shared__ __align__(16) float nvs[8192];            // [0..4095]=nv half; full=scratch
  __shared__ float l_lds[64];

  const int t = threadIdx.x;
  const int lane = t & 63;
  const int w = t >> 6;
  const int cf = w & 7;
  const int ks = w >> 3;
  const int r = t >> 5;              // score row 0..31 (per rowgroup)
  const int p2 = t & 31;             // col pair 2p2,2p2+1 (of 64)
  const int i0 = blockIdx.x * 64;
  const int jh = blockIdx.y;
  const size_t jbase = (size_t)jh * 4096;
  const int jt = jh * 128;           // tile32 base

  reinterpret_cast<float4*>(nvs)[t] = reinterpret_cast<const float4*>(nv + jbase)[t];

  const float svrA = sv[i0 + r];
  const float svrB = sv[i0 + 32 + r];
  const size_t mrowA = (size_t)(i0 + r) * NN + jbase;
  const size_t mrowB = mrowA + (size_t)32 * NN;
  const uint* mkrowA = Bm + (size_t)(i0 + r) * (NN / 32) + jh * 128;
  const uint* mkrowB = mkrowA + (size_t)32 * (NN / 32);
  const int col = cf * 32 + (lane & 31);
  const size_t bo0 = ((size_t)(lane >> 5) * F + col) * 8;
  const int pidx = (p2 >> 2) * 132 + r * 4 + (p2 & 3);
  const int aidx = (ks * 4 + (lane >> 5)) * 132 + (lane & 31) * 4;

  float2 MA_e = *reinterpret_cast<const float2*>(&Mm[mrowA + 2 * p2]);
  float2 MA_o = *reinterpret_cast<const float2*>(&Mm[mrowA + 64 + 2 * p2]);
  float2 MB_e = *reinterpret_cast<const float2*>(&Mm[mrowB + 2 * p2]);
  float2 MB_o = *reinterpret_cast<const float2*>(&Mm[mrowB + 64 + 2 * p2]);
  uint mkA_e = mkrowA[p2 >> 4];
  uint mkA_o = mkrowA[2 + (p2 >> 4)];
  uint mkB_e = mkrowB[p2 >> 4];
  uint mkB_o = mkrowB[2 + (p2 >> 4)];
  const size_t tb0 = (size_t)(jt + ks) * 8192;
  bf16x8 bh0_e = *reinterpret_cast<const bf16x8*>(Th + tb0 + bo0);
  bf16x8 bl0_e = *reinterpret_cast<const bf16x8*>(Tl + tb0 + bo0);
  bf16x8 bh1_e = *reinterpret_cast<const bf16x8*>(Th + tb0 + bo0 + 4096);
  bf16x8 bl1_e = *reinterpret_cast<const bf16x8*>(Tl + tb0 + bo0 + 4096);
  bf16x8 bh0_o, bl0_o, bh1_o, bl1_o;

  float rsumA = 0.f, rsumB = 0.f;
  f32x16 accA, accB;
  #pragma unroll
  for (int i = 0; i < 16; ++i) { accA[i] = 0.f; accB[i] = 0.f; }

  __syncthreads();   // nvs staged

  float2 nv_e = *reinterpret_cast<const float2*>(&nvs[2 * p2]);
  float2 nv_o = *reinterpret_cast<const float2*>(&nvs[64 + 2 * p2]);

#define STEP1(TJ, MCA, MKA, MCB, MKB, NVC, BH0C, BL0C, BH1C, BL1C, BH0N, BL0N, BH1N, BL1N) \
  {                                                                               \
    const int t_j = (TJ);                                                         \
    const int jb = (t_j + 1 < NT) ? t_j + 1 : 0;                                  \
    const size_t tb = (size_t)(jt + 2 * jb + ks) * 8192;                          \
    BH0N = *reinterpret_cast<const bf16x8*>(Th + tb + bo0);                       \
    BL0N = *reinterpret_cast<const bf16x8*>(Tl + tb + bo0);                       \
    BH1N = *reinterpret_cast<const bf16x8*>(Th + tb + bo0 + 4096);                \
    BL1N = *reinterpret_cast<const bf16x8*>(Tl + tb + bo0 + 4096);                \
    float e0 = (svrA + NVC.x) * MCA.x; e0 = fmaxf(e0, 0.2f * e0); e0 = fminf(e0, 70.f); \
    float e1 = (svrA + NVC.y) * MCA.y; e1 = fmaxf(e1, 0.2f * e1); e1 = fminf(e1, 70.f); \
    float e2 = (svrB + NVC.x) * MCB.x; e2 = fmaxf(e2, 0.2f * e2); e2 = fminf(e2, 70.f); \
    float e3 = (svrB + NVC.y) * MCB.y; e3 = fmaxf(e3, 0.2f * e3); e3 = fminf(e3, 70.f); \
    const float pA0 = ((MKA >> (2 * (p2 & 15))) & 1u) ? __expf(e0) : 0.f;         \
    const float pA1 = ((MKA >> (2 * (p2 & 15) + 1)) & 1u) ? __expf(e1) : 0.f;     \
    const float pB0 = ((MKB >> (2 * (p2 & 15))) & 1u) ? __expf(e2) : 0.f;         \
    const float pB1 = ((MKB >> (2 * (p2 & 15) + 1)) & 1u) ? __expf(e3) : 0.f;     \
    rsumA += pA0 + pA1; rsumB += pB0 + pB1;                                       \
    const int jm = (t_j + 2 < NT) ? t_j + 2 : 0;                                  \
    MCA = *reinterpret_cast<const float2*>(&Mm[mrowA + (size_t)jm * 64 + 2 * p2]); \
    MKA = mkrowA[jm * 2 + (p2 >> 4)];                                             \
    MCB = *reinterpret_cast<const float2*>(&Mm[mrowB + (size_t)jm * 64 + 2 * p2]); \
    MKB = mkrowB[jm * 2 + (p2 >> 4)];                                             \
    NVC = *reinterpret_cast<const float2*>(&nvs[jm * 64 + 2 * p2]);               \
    const uint hwA = cvt_pk_bf16(pA0, pA1);                                       \
    const uint lwA = cvt_pk_bf16(pA0 - __uint_as_float(hwA << 16),                \
                                 pA1 - __uint_as_float(hwA & 0xffff0000u));       \
    const uint hwB = cvt_pk_bf16(pB0, pB1);                                       \
    const uint lwB = cvt_pk_bf16(pB0 - __uint_as_float(hwB << 16),                \
                                 pB1 - __uint_as_float(hwB & 0xffff0000u));       \
    Pa[t_j & 1][0][0][pidx] = hwA;                                                \
    Pa[t_j & 1][1][0][pidx] = lwA;                                                \
    Pa[t_j & 1][0][1][pidx] = hwB;                                                \
    Pa[t_j & 1][1][1][pidx] = lwB;                                                \
    lds_barrier();                                                                \
    const bf16x8 ahA0 = *reinterpret_cast<const bf16x8*>(&Pa[t_j & 1][0][0][aidx]);       \
    const bf16x8 alA0 = *reinterpret_cast<const bf16x8*>(&Pa[t_j & 1][1][0][aidx]);       \
    const bf16x8 ahA1 = *reinterpret_cast<const bf16x8*>(&Pa[t_j & 1][0][0][aidx + 264]); \
    const bf16x8 alA1 = *reinterpret_cast<const bf16x8*>(&Pa[t_j & 1][1][0][aidx + 264]); \
    const bf16x8 ahB0 = *reinterpret_cast<const bf16x8*>(&Pa[t_j & 1][0][1][aidx]);       \
    const bf16x8 alB0 = *reinterpret_cast<const bf16x8*>(&Pa[t_j & 1][1][1][aidx]);       \
    const bf16x8 ahB1 = *reinterpret_cast<const bf16x8*>(&Pa[t_j & 1][0][1][aidx + 264]); \
    const bf16x8 alB1 = *reinterpret_cast<const bf16x8*>(&Pa[t_j & 1][1][1][aidx + 264]); \
    accA = __builtin_amdgcn_mfma_f32_32x32x16_bf16(alA0, BH0C, accA, 0, 0, 0);    \
    accB = __builtin_amdgcn_mfma_f32_32x32x16_bf16(alB0, BH0C, accB, 0, 0, 0);    \
    accA = __builtin_amdgcn_mfma_f32_32x32x16_bf16(ahA0, BL0C, accA, 0, 0, 0);    \
    accB = __builtin_amdgcn_mfma_f32_32x32x16_bf16(ahB0, BL0C, accB, 0, 0, 0);    \
    accA = __builtin_amdgcn_mfma_f32_32x32x16_bf16(ahA0, BH0C, accA, 0, 0, 0);    \
    accB = __builtin_amdgcn_mfma_f32_32x32x16_bf16(ahB0, BH0C, accB, 0, 0, 0);    \
    accA = __builtin_amdgcn_mfma_f32_32x32x16_bf16(alA1, BH1C, accA, 0, 0, 0);    \
    accB = __builtin_amdgcn_mfma_f32_32x32x16_bf16(alB1, BH1C, accB, 0, 0, 0);    \
    accA = __builtin_amdgcn_mfma_f32_32x32x16_bf16(ahA1, BL1C, accA, 0, 0, 0);    \
    accB = __builtin_amdgcn_mfma_f32_32x32x16_bf16(ahB1, BL1C, accB, 0, 0, 0);    \
    accA = __builtin_amdgcn_mfma_f32_32x32x16_bf16(ahA1, BH1C, accA, 0, 0, 0);    \
    accB = __builtin_amdgcn_mfma_f32_32x32x16_bf16(ahB1, BH1C, accB, 0, 0, 0);    \
  }

  for (int tj = 0; tj < NT; tj += 2) {
    STEP1(tj,     MA_e, mkA_e, MB_e, mkB_e, nv_e, bh0_e, bl0_e, bh1_e, bl1_e, bh0_o, bl0_o, bh1_o, bl1_o)
    STEP1(tj + 1, MA_o, mkA_o, MB_o, mkB_o, nv_o, bh0_o, bl0_o, bh1_o, bl1_o, bh0_e, bl0_e, bh1_e, bl1_e)
  }
#undef STEP1

  #pragma unroll
  for (int off = 1; off < 32; off <<= 1) {
    rsumA += __shfl_xor(rsumA, off);
    rsumB += __shfl_xor(rsumB, off);
  }
  if (p2 == 0) { l_lds[r] = rsumA; l_lds[32 + r] = rsumB; }
  __syncthreads();
  if (t < 64) pL[(size_t)jh * 8192 + i0 + t] = l_lds[t];

  // k-half reduce via LDS scratch (reuse nvs, 32KB), rowgroup A then B.
  float* scratch = nvs;
  if (ks == 1) {
    #pragma unroll
    for (int reg = 0; reg < 16; ++reg) scratch[cf * 1024 + reg * 64 + lane] = accA[reg];
  }
  __syncthreads();
  if (ks == 0) {
    #pragma unroll
    for (int reg = 0; reg < 16; ++reg) {
      const int row = (reg & 3) + 8 * (reg >> 2) + 4 * (lane >> 5);
      pO[(size_t)jh * 8192 * F + (size_t)(i0 + row) * F + col] =
          accA[reg] + scratch[cf * 1024 + reg * 64 + lane];
    }
  }
  __syncthreads();
  if (ks == 1) {
    #pragma unroll
    for (int reg = 0; reg < 16; ++reg) scratch[cf * 1024 + reg * 64 + lane] = accB[reg];
  }
  __syncthreads();
  if (ks == 0) {
    #pragma unroll
    for (int reg = 0; reg < 16; ++reg) {
      const int row = (reg & 3) + 8 * (reg >> 2) + 4 * (lane >> 5);
      pO[(size_t)jh * 8192 * F + (size_t)(i0 + 32 + row) * F + col] =
          accB[reg] + scratch[cf * 1024 + reg * 64 + lane];
    }
  }
}

// ---------------------------------------------------------------------------
// Layer-2 fused attention. Grid (128,2): 64 rows x j-half, 1024 thr.
// ---------------------------------------------------------------------------
__global__ __launch_bounds__(1024, 4) void attn2_kernel(
    const float* __restrict__ Mm, const uint* __restrict__ Bm,
    const float* __restrict__ sv, const float* __restrict__ nv,
    const unsigned short* __restrict__ Th, const unsigned short* __restrict__ Tl,
    float* __restrict__ pO, float* __restrict__ pL) {
  constexpr int F = 64, NT = 4096 / 64;
  __shared__ __align__(16) uint Pa[2][2][2][8 * 132];
  __shared__ __align__(16) float nvs[4096];
  __shared__ float l_lds[64];

  const int t = threadIdx.x;
  const int lane = t & 63;
  const int w = t >> 6;
  const int rb = w & 1;
  const int cf = (w >> 1) & 3;
  const int ks = w >> 3;
  const int r = t >> 5;
  const int p2 = t & 31;
  const int i0 = blockIdx.x * 64;
  const int jh = blockIdx.y;
  const size_t jbase = (size_t)jh * 4096;
  const int jt = jh * 128;

  reinterpret_cast<float4*>(nvs)[t] = reinterpret_cast<const float4*>(nv + jbase)[t];

  const float svrA = sv[i0 + r];
  const float svrB = sv[i0 + 32 + r];
  const size_t mrowA = (size_t)(i0 + r) * NN + jbase;
  const size_t mrowB = mrowA + (size_t)32 * NN;
  const uint* mkrowA = Bm + (size_t)(i0 + r) * (NN / 32) + jh * 128;
  const uint* mkrowB = mkrowA + (size_t)32 * (NN / 32);
  const int col = cf * 16 + (lane & 15);
  const size_t bo2 = ((size_t)(lane >> 4) * F + col) * 8;
  const int pidx = (p2 >> 2) * 132 + r * 4 + (p2 & 3);
  const int aidx = (ks * 4 + (lane >> 4)) * 132 + (rb * 16 + (lane & 15)) * 4;

  float2 MA_e = *reinterpret_cast<const float2*>(&Mm[mrowA + 2 * p2]);
  float2 MA_o = *reinterpret_cast<const float2*>(&Mm[mrowA + 64 + 2 * p2]);
  float2 MB_e = *reinterpret_cast<const float2*>(&Mm[mrowB + 2 * p2]);
  float2 MB_o = *reinterpret_cast<const float2*>(&Mm[mrowB + 64 + 2 * p2]);
  uint mkA_e = mkrowA[p2 >> 4];
  uint mkA_o = mkrowA[2 + (p2 >> 4)];
  uint mkB_e = mkrowB[p2 >> 4];
  uint mkB_o = mkrowB[2 + (p2 >> 4)];
  const size_t tb0 = (size_t)(jt + ks) * 2048;
  bf16x8 bh_e = *reinterpret_cast<const bf16x8*>(Th + tb0 + bo2);
  bf16x8 bl_e = *reinterpret_cast<const bf16x8*>(Tl + tb0 + bo2);
  bf16x8 bh_o, bl_o;

  float rsumA = 0.f, rsumB = 0.f;
  f32x4 accA = {0.f, 0.f, 0.f, 0.f}, accA2 = {0.f, 0.f, 0.f, 0.f};
  f32x4 accB = {0.f, 0.f, 0.f, 0.f}, accB2 = {0.f, 0.f, 0.f, 0.f};

  __syncthreads();   // nvs staged

  float2 nv_e = *reinterpret_cast<const float2*>(&nvs[2 * p2]);
  float2 nv_o = *reinterpret_cast<const float2*>(&nvs[64 + 2 * p2]);

#define STEP2(TJ, MCA, MKA, MCB, MKB, NVC, BHC, BLC, BHN, BLN)                    \
  {                                                                               \
    const int t_j = (TJ);                                                         \
    const int jb = (t_j + 1 < NT) ? t_j + 1 : 0;                                  \
    const size_t tb = (size_t)(jt + 2 * jb + ks) * 2048;                          \
    BHN = *reinterpret_cast<const bf16x8*>(Th + tb + bo2);                        \
    BLN = *reinterpret_cast<const bf16x8*>(Tl + tb + bo2);                        \
    float e0 = (svrA + NVC.x) * MCA.x; e0 = fmaxf(e0, 0.2f * e0); e0 = fminf(e0, 70.f); \
    float e1 = (svrA + NVC.y) * MCA.y; e1 = fmaxf(e1, 0.2f * e1); e1 = fminf(e1, 70.f); \
    float e2 = (svrB + NVC.x) * MCB.x; e2 = fmaxf(e2, 0.2f * e2); e2 = fminf(e2, 70.f); \
    float e3 = (svrB + NVC.y) * MCB.y; e3 = fmaxf(e3, 0.2f * e3); e3 = fminf(e3, 70.f); \
    const float pA0 = ((MKA >> (2 * (p2 & 15))) & 1u) ? __expf(e0) : 0.f;         \
    const float pA1 = ((MKA >> (2 * (p2 & 15) + 1)) & 1u) ? __expf(e1) : 0.f;     \
    const float pB0 = ((MKB >> (2 * (p2 & 15))) & 1u) ? __expf(e2) : 0.f;         \
    const float pB1 = ((MKB >> (2 * (p2 & 15) + 1)) & 1u) ? __expf(e3) : 0.f;     \
    rsumA += pA0 + pA1; rsumB += pB0 + pB1;                                       \
    const int jm = (t_j + 2 < NT) ? t_j + 2 : 0;                                  \
    MCA = *reinterpret_cast<const float2*>(&Mm[mrowA + (size_t)jm * 64 + 2 * p2]); \
    MKA = mkrowA[jm * 2 + (p2 >> 4)];                                             \
    MCB = *reinterpret_cast<const float2*>(&Mm[mrowB + (size_t)jm * 64 + 2 * p2]); \
    MKB = mkrowB[jm * 2 + (p2 >> 4)];                                             \
    NVC = *reinterpret_cast<const float2*>(&nvs[jm * 64 + 2 * p2]);               \
    const uint hwA = cvt_pk_bf16(pA0, pA1);                                       \
    const uint lwA = cvt_pk_bf16(pA0 - __uint_as_float(hwA << 16),                \
                                 pA1 - __uint_as_float(hwA & 0xffff0000u));       \
    const uint hwB = cvt_pk_bf16(pB0, pB1);                                       \
    const uint lwB = cvt_pk_bf16(pB0 - __uint_as_float(hwB << 16),                \
                                 pB1 - __uint_as_float(hwB & 0xffff0000u));       \
    Pa[t_j & 1][0][0][pidx] = hwA;                                                \
    Pa[t_j & 1][1][0][pidx] = lwA;                                                \
    Pa[t_j & 1][0][1][pidx] = hwB;                                                \
    Pa[t_j & 1][1][1][pidx] = lwB;                                                \
    lds_barrier();                                                                \
    const bf16x8 ahA = *reinterpret_cast<const bf16x8*>(&Pa[t_j & 1][0][0][aidx]); \
    const bf16x8 alA = *reinterpret_cast<const bf16x8*>(&Pa[t_j & 1][1][0][aidx]); \
    const bf16x8 ahB = *reinterpret_cast<const bf16x8*>(&Pa[t_j & 1][0][1][aidx]); \
    const bf16x8 alB = *reinterpret_cast<const bf16x8*>(&Pa[t_j & 1][1][1][aidx]); \
    accA  = __builtin_amdgcn_mfma_f32_16x16x32_bf16(alA, BHC, accA, 0, 0, 0);     \
    accB  = __builtin_amdgcn_mfma_f32_16x16x32_bf16(alB, BHC, accB, 0, 0, 0);     \
    accA2 = __builtin_amdgcn_mfma_f32_16x16x32_bf16(ahA, BLC, accA2, 0, 0, 0);    \
    accB2 = __builtin_amdgcn_mfma_f32_16x16x32_bf16(ahB, BLC, accB2, 0, 0, 0);    \
    accA  = __builtin_amdgcn_mfma_f32_16x16x32_bf16(ahA, BHC, accA, 0, 0, 0);     \
    accB  = __builtin_amdgcn_mfma_f32_16x16x32_bf16(ahB, BHC, accB, 0, 0, 0);     \
  }

  for (int tj = 0; tj < NT; tj += 2) {
    STEP2(tj,     MA_e, mkA_e, MB_e, mkB_e, nv_e, bh_e, bl_e, bh_o, bl_o)
    STEP2(tj + 1, MA_o, mkA_o, MB_o, mkB_o, nv_o, bh_o, bl_o, bh_e, bl_e)
  }
#undef STEP2

  #pragma unroll
  for (int off = 1; off < 32; off <<= 1) {
    rsumA += __shfl_xor(rsumA, off);
    rsumB += __shfl_xor(rsumB, off);
  }
  if (p2 == 0) { l_lds[r] = rsumA; l_lds[32 + r] = rsumB; }
  __syncthreads();
  if (t < 64) pL[(size_t)jh * 8192 + i0 + t] = l_lds[t];

  float* scratch = nvs;
  if (ks == 1) {
    #pragma unroll
    for (int reg = 0; reg < 4; ++reg)
      scratch[(w & 7) * 256 + reg * 64 + lane] = accA[reg] + accA2[reg];
  }
  __syncthreads();
  if (ks == 0) {
    #pragma unroll
    for (int reg = 0; reg < 4; ++reg) {
      const int row = rb * 16 + (lane >> 4) * 4 + reg;
      pO[(size_t)jh * 8192 * F + (size_t)(i0 + row) * F + col] =
          accA[reg] + accA2[reg] + scratch[(w & 7) * 256 + reg * 64 + lane];
    }
  }
  __syncthreads();
  if (ks == 1) {
    #pragma unroll
    for (int reg = 0; reg < 4; ++reg)
      scratch[(w & 7) * 256 + reg * 64 + lane] = accB[reg] + accB2[reg];
  }
  __syncthreads();
  if (ks == 0) {
    #pragma unroll
    for (int reg = 0; reg < 4; ++reg) {
      const int row = rb * 16 + (lane >> 4) * 4 + reg;
      pO[(size_t)jh * 8192 * F + (size_t)(i0 + 32 + row) * F + col] =
          accB[reg] + accB2[reg] + scratch[(w & 7) * 256 + reg * 64 + lane];
    }
  }
}

// ---------------------------------------------------------------------------
extern "C" void kernel_launch(void* const* d_in, const int* in_sizes, int n_in,
                              void* d_out, int out_size, void* d_ws, size_t ws_size,
                              hipStream_t stream) {
  const float* x   = (const float*)d_in[0];
  const int*   adj = (const int*)  d_in[1];
  const float* Mm  = (const float*)d_in[2];
  const float* W0  = (const float*)d_in[3];
  const float* as0 = (const float*)d_in[4];
  const float* an0 = (const float*)d_in[5];
  const float* W1  = (const float*)d_in[6];
  const float* as1 = (const float*)d_in[7];
  const float* an1 = (const float*)d_in[8];
  float* out = (float*)d_out;

  char* ws = (char*)d_ws;
  const size_t MB = 1048576;
  const size_t KB = 1024;
  unsigned short* Th0 = (unsigned short*)(ws + 18 * MB);  // 4 MB
  unsigned short* Tl0 = (unsigned short*)(ws + 22 * MB);  // 4 MB
  unsigned short* Th1 = (unsigned short*)(ws + 26 * MB);  // 1 MB
  unsigned short* Tl1 = (unsigned short*)(ws + 27 * MB);  // 1 MB
  float* s0  = (float*)(ws + 28 * MB);
  float* n0  = (float*)(ws + 28 * MB + 32 * KB);
  float* s1  = (float*)(ws + 28 * MB + 64 * KB);
  float* n1  = (float*)(ws + 28 * MB + 96 * KB);
  float* pL1 = (float*)(ws + 28 * MB + 128 * KB);         // 64 KB [2][8192]
  float* pL2 = (float*)(ws + 28 * MB + 192 * KB);         // 64 KB
  float* pO1 = (float*)(ws + 29 * MB);                    // 16 MB [2][8192][256]
  float* pO2 = (float*)(ws + 29 * MB);                    // 4 MB  [2][8192][64] (pO1 dead)
  unsigned short* Txh = (unsigned short*)(ws + 64 * MB);  // 8 MB (x split hi)
  unsigned short* Txl = (unsigned short*)(ws + 72 * MB);  // 8 MB (x split lo)
  unsigned short* Twh = (unsigned short*)(ws + 80 * MB);  // 256 KB (W0 split hi)
  unsigned short* Twl = (unsigned short*)(ws + 81 * MB);  // 256 KB (W0 split lo)
  uint*  Bm  = (uint*)(ws + 82 * MB);                     // 8 MB

  // ---- prep: splitx + splitw + mask in one launch ----
  prep_kernel<<<dim3(66112), dim3(256), 0, stream>>>(x, W0, adj, Txh, Txl, Twh, Twl, Bm);
  // ---- layer 1 (gemm1 fuses split1 + sn1; h0 never materialized) ----
  gemm1_mfma_kernel<<<dim3(256), dim3(512), 0, stream>>>(Txh, Txl, Twh, Twl,
                                                         as0, an0, Th0, Tl0, s0, n0);
  attn1_kernel<<<dim3(128, 2), dim3(1024), 0, stream>>>(Mm, Bm, s0, n0, Th0, Tl0, pO1, pL1);
  // ---- layer 2 (combine1+gemm2+sn2+split2 fused; il inline) ----
  gemm2_fused_kernel<<<dim3(128), dim3(256), 0, stream>>>(pO1, pL1, W1, as1, an1,
                                                          Th1, Tl1, s1, n1);
  attn2_kernel<<<dim3(128, 2), dim3(1024), 0, stream>>>(Mm, Bm, s1, n1, Th1, Tl1, pO2, pL2);
  combine_kernel<64><<<dim3(512), dim3(256), 0, stream>>>(pO2, pL2, out);
}